// Round 3
// baseline (382.292 us; speedup 1.0000x reference)
//
#include <hip/hip_runtime.h>
#include <stdint.h>

// Problem geometry (fixed)
#define HW     16384      // 128*128
#define IMGW   128
#define NCH    768        // 3*DIM
#define DIMC   256
#define NB     2
#define CPH    32         // channels per head

// ---------------------------------------------------------------------------
// K1/K7: C[M,HW] = A[M,256] * B[256,HW]  (fp32 in, fp32 accumulate, fp32 out)
// block 256 thr, tile 64(m) x 128(n), BK=16, per-thread 4x8 microtile
// ---------------------------------------------------------------------------
__global__ __launch_bounds__(256)
void gemm_k256(const float* __restrict__ A, long aStride,
               const float* __restrict__ Bm, long bStride,
               float* __restrict__ Cm, long cStride)
{
    __shared__ float As[16][68];    // [k][m], padded
    __shared__ float Bs[16][132];   // [k][n], padded

    const int t  = threadIdx.x;
    const int bz = blockIdx.z;
    const int m0 = blockIdx.y * 64;
    const int n0 = blockIdx.x * 128;

    const float* Ab = A  + (size_t)bz * aStride;
    const float* Bb = Bm + (size_t)bz * bStride;

    const int ty = t >> 4, tx = t & 15;
    const int mb = ty * 4, nb = tx * 8;

    float acc[4][8];
    #pragma unroll
    for (int i = 0; i < 4; ++i)
        #pragma unroll
        for (int j = 0; j < 8; ++j) acc[i][j] = 0.f;

    const int a_m = t >> 2;            // 0..63
    const int a_k = (t & 3) << 2;      // 0,4,8,12

    for (int k0 = 0; k0 < 256; k0 += 16) {
        __syncthreads();
        // A tile: 64x16, float4 along k, stored transposed [k][m]
        float4 a4 = *reinterpret_cast<const float4*>(Ab + (size_t)(m0 + a_m) * 256 + k0 + a_k);
        As[a_k + 0][a_m] = a4.x;
        As[a_k + 1][a_m] = a4.y;
        As[a_k + 2][a_m] = a4.z;
        As[a_k + 3][a_m] = a4.w;
        // B tile: 16x128, 2 float4 per thread
        #pragma unroll
        for (int r = 0; r < 2; ++r) {
            int idx = t + r * 256;
            int br = idx >> 5, bc = (idx & 31) << 2;
            *reinterpret_cast<float4*>(&Bs[br][bc]) =
                *reinterpret_cast<const float4*>(Bb + (size_t)(k0 + br) * HW + n0 + bc);
        }
        __syncthreads();
        #pragma unroll
        for (int kk = 0; kk < 16; ++kk) {
            float4 av  = *reinterpret_cast<const float4*>(&As[kk][mb]);
            float4 bv0 = *reinterpret_cast<const float4*>(&Bs[kk][nb]);
            float4 bv1 = *reinterpret_cast<const float4*>(&Bs[kk][nb + 4]);
            float ae[4] = {av.x, av.y, av.z, av.w};
            float be[8] = {bv0.x, bv0.y, bv0.z, bv0.w, bv1.x, bv1.y, bv1.z, bv1.w};
            #pragma unroll
            for (int i = 0; i < 4; ++i)
                #pragma unroll
                for (int j = 0; j < 8; ++j)
                    acc[i][j] = fmaf(ae[i], be[j], acc[i][j]);
        }
    }

    #pragma unroll
    for (int i = 0; i < 4; ++i) {
        float4 lo = {acc[i][0], acc[i][1], acc[i][2], acc[i][3]};
        float4 hi = {acc[i][4], acc[i][5], acc[i][6], acc[i][7]};
        float* p = Cm + (size_t)bz * cStride + (size_t)(m0 + mb + i) * HW + n0 + nb;
        *reinterpret_cast<float4*>(p)     = lo;
        *reinterpret_cast<float4*>(p + 4) = hi;
    }
}

// ---------------------------------------------------------------------------
// K2: depthwise 3x3 SAME (cross-correlation, per-channel weights)
// ---------------------------------------------------------------------------
__global__ __launch_bounds__(256)
void dwconv3(const float* __restrict__ in, const float* __restrict__ wdw,
             float* __restrict__ out)
{
    const int p  = blockIdx.y;                 // plane = bi*768 + ch
    const int t  = threadIdx.x;
    const int r  = blockIdx.x * 8 + (t >> 5);
    const int c0 = (t & 31) << 2;

    const float* plane = in + (size_t)p * HW;
    const float* wp = wdw + (p % NCH) * 9;
    float w[9];
    #pragma unroll
    for (int i = 0; i < 9; ++i) w[i] = wp[i];

    float acc[4] = {0.f, 0.f, 0.f, 0.f};
    #pragma unroll
    for (int dy = -1; dy <= 1; ++dy) {
        int ry = r + dy;
        if (ry < 0 || ry >= IMGW) continue;
        const float* rowp = plane + ry * IMGW;
        float4 vm = *reinterpret_cast<const float4*>(rowp + c0);
        float vl = (c0 > 0)   ? rowp[c0 - 1] : 0.f;
        float vr = (c0 < 124) ? rowp[c0 + 4] : 0.f;
        float vals[6] = {vl, vm.x, vm.y, vm.z, vm.w, vr};
        int wr = (dy + 1) * 3;
        #pragma unroll
        for (int dx = 0; dx < 3; ++dx) {
            float wv = w[wr + dx];
            #pragma unroll
            for (int q = 0; q < 4; ++q)
                acc[q] = fmaf(vals[q + dx], wv, acc[q]);
        }
    }
    float4 o4 = {acc[0], acc[1], acc[2], acc[3]};
    *reinterpret_cast<float4*>(out + (size_t)p * HW + r * IMGW + c0) = o4;
}

// ---------------------------------------------------------------------------
// K3: inverse l2 norms of q,k rows. grid = B*512 blocks (one per row)
// ---------------------------------------------------------------------------
__global__ __launch_bounds__(256)
void l2norm_inv(const float* __restrict__ dw, float* __restrict__ invn)
{
    const int idx = blockIdx.x;          // 0..1023
    const int bi  = idx >> 9;
    const int ch  = idx & 511;           // q: 0..255, k: 256..511
    const float* row = dw + ((size_t)bi * NCH + ch) * HW;

    float s = 0.f;
    for (int i = threadIdx.x; i < HW / 4; i += 256) {
        float4 v = reinterpret_cast<const float4*>(row)[i];
        s = fmaf(v.x, v.x, s); s = fmaf(v.y, v.y, s);
        s = fmaf(v.z, v.z, s); s = fmaf(v.w, v.w, s);
    }
    #pragma unroll
    for (int off = 32; off; off >>= 1) s += __shfl_down(s, off);
    __shared__ float red[4];
    if ((threadIdx.x & 63) == 0) red[threadIdx.x >> 6] = s;
    __syncthreads();
    if (threadIdx.x == 0) {
        float tot = red[0] + red[1] + red[2] + red[3];
        invn[idx] = 1.f / fmaxf(sqrtf(tot), 1e-12f);
    }
}

// ---------------------------------------------------------------------------
// K4: Gram partials. grid (16 n-chunks, 16 bh). part: [chunk][bh][32*32]
// ---------------------------------------------------------------------------
__global__ __launch_bounds__(256)
void gram_partial(const float* __restrict__ dw, float* __restrict__ part)
{
    __shared__ float Qs[32][132];
    __shared__ float Ks[32][132];
    const int chunk = blockIdx.x;
    const int bh    = blockIdx.y;
    const int bi = bh >> 3, h = bh & 7;
    const float* qbase = dw + ((size_t)bi * NCH + h * CPH) * HW;
    const float* kbase = dw + ((size_t)bi * NCH + 256 + h * CPH) * HW;
    const int t = threadIdx.x;
    const int c = t >> 3, d0 = (t & 7) << 2;

    float acc[4] = {0.f, 0.f, 0.f, 0.f};
    for (int sub = 0; sub < 8; ++sub) {
        int nbase = chunk * 1024 + sub * 128;
        __syncthreads();
        #pragma unroll
        for (int r = 0; r < 4; ++r) {
            int idx = t + r * 256;
            int row = idx >> 5, col = (idx & 31) << 2;
            *reinterpret_cast<float4*>(&Qs[row][col]) =
                *reinterpret_cast<const float4*>(qbase + (size_t)row * HW + nbase + col);
            *reinterpret_cast<float4*>(&Ks[row][col]) =
                *reinterpret_cast<const float4*>(kbase + (size_t)row * HW + nbase + col);
        }
        __syncthreads();
        #pragma unroll 8
        for (int n4 = 0; n4 < 32; ++n4) {
            float4 q4 = *reinterpret_cast<const float4*>(&Qs[c][n4 << 2]);
            #pragma unroll
            for (int j = 0; j < 4; ++j) {
                float4 k4 = *reinterpret_cast<const float4*>(&Ks[d0 + j][n4 << 2]);
                acc[j] = fmaf(q4.x, k4.x, acc[j]);
                acc[j] = fmaf(q4.y, k4.y, acc[j]);
                acc[j] = fmaf(q4.z, k4.z, acc[j]);
                acc[j] = fmaf(q4.w, k4.w, acc[j]);
            }
        }
    }
    float4 o4 = {acc[0], acc[1], acc[2], acc[3]};
    *reinterpret_cast<float4*>(part + ((size_t)chunk * 16 + bh) * 1024 + c * 32 + d0) = o4;
}

// ---------------------------------------------------------------------------
// K4b: reduce partials + apply inv norms and temperature
// ---------------------------------------------------------------------------
__global__ __launch_bounds__(256)
void gram_finish(const float* __restrict__ part, const float* __restrict__ invn,
                 const float* __restrict__ temp, float* __restrict__ attn)
{
    const int idx = blockIdx.x * 256 + threadIdx.x;  // 0..16383
    const int bh = idx >> 10;
    const int bi = bh >> 3, h = bh & 7;
    const int c = (idx >> 5) & 31, d = idx & 31;
    float s = 0.f;
    #pragma unroll
    for (int ch = 0; ch < 16; ++ch) s += part[(size_t)ch * 16384 + idx];
    float iq = invn[bi * 512 + h * CPH + c];
    float ik = invn[bi * 512 + 256 + h * CPH + d];
    attn[idx] = s * iq * ik * temp[h];
}

// ---------------------------------------------------------------------------
// K5: rank-based 4-way sparse softmax combine. One block (1024 thr) per bh.
// ---------------------------------------------------------------------------
__global__ __launch_bounds__(1024)
void sparse_softmax(const float* __restrict__ attn, float* __restrict__ spar,
                    const float* __restrict__ a1, const float* __restrict__ a2,
                    const float* __restrict__ a3, const float* __restrict__ a4)
{
    __shared__ float xs[1024];
    __shared__ float red[16 * 4];
    __shared__ float vthr[4];
    __shared__ float msh;
    __shared__ float ssh[4];

    const int bh = blockIdx.x, t = threadIdx.x;
    float x = attn[bh * 1024 + t];
    xs[t] = x;
    __syncthreads();

    int g = 0, e = 0;
    for (int j = 0; j < 1024; ++j) {
        float v = xs[j];
        g += (v > x);
        e += (v == x);
    }
    if (g == 0) msh = x;  // all writers hold the identical max value
    const int topks[4] = {512, 682, 768, 819};
    #pragma unroll
    for (int kk = 0; kk < 4; ++kk)
        if (g <= topks[kk] - 1 && topks[kk] - 1 < g + e) vthr[kk] = x;  // rank-(topk-1) value
    __syncthreads();

    float m  = msh;
    float ex = expf(x - m);
    float v4[4];
    #pragma unroll
    for (int kk = 0; kk < 4; ++kk) v4[kk] = (x >= vthr[kk]) ? ex : 0.f;
    #pragma unroll
    for (int off = 32; off; off >>= 1)
        #pragma unroll
        for (int kk = 0; kk < 4; ++kk) v4[kk] += __shfl_down(v4[kk], off);
    const int lane = t & 63, wid = t >> 6;
    if (lane == 0) {
        #pragma unroll
        for (int kk = 0; kk < 4; ++kk) red[wid * 4 + kk] = v4[kk];
    }
    __syncthreads();
    if (t == 0) {
        float s0 = 0, s1 = 0, s2 = 0, s3 = 0;
        for (int w = 0; w < 16; ++w) {
            s0 += red[w * 4 + 0]; s1 += red[w * 4 + 1];
            s2 += red[w * 4 + 2]; s3 += red[w * 4 + 3];
        }
        ssh[0] = s0; ssh[1] = s1; ssh[2] = s2; ssh[3] = s3;
    }
    __syncthreads();

    float av[4] = {*a1, *a2, *a3, *a4};
    float coef = 0.f;
    #pragma unroll
    for (int kk = 0; kk < 4; ++kk)
        if (x >= vthr[kk]) coef += av[kk] / ssh[kk];
    spar[bh * 1024 + t] = ex * coef;
}

// ---------------------------------------------------------------------------
// K6: M2[b][o][h*32+d] = sum_cc Wproj[o][h*32+cc] * spar[b,h,cc,d]
// ---------------------------------------------------------------------------
__global__ __launch_bounds__(256)
void build_m2(const float* __restrict__ wproj, const float* __restrict__ spar,
              float* __restrict__ m2)
{
    const int idx = blockIdx.x * 256 + threadIdx.x;  // 0..131071
    const int b = idx >> 16, o = (idx >> 8) & 255, hd = idx & 255;
    const int h = hd >> 5, d = hd & 31;
    const float* wrow = wproj + o * 256 + h * CPH;
    const float* sp = spar + (size_t)(b * 8 + h) * 1024 + d;
    float acc = 0.f;
    #pragma unroll 8
    for (int cc = 0; cc < 32; ++cc)
        acc = fmaf(wrow[cc], sp[cc * 32], acc);
    m2[idx] = acc;
}

// ---------------------------------------------------------------------------
// launch
// ---------------------------------------------------------------------------
extern "C" void kernel_launch(void* const* d_in, const int* in_sizes, int n_in,
                              void* d_out, int out_size, void* d_ws, size_t ws_size,
                              hipStream_t stream)
{
    const float* x      = (const float*)d_in[0];
    const float* w_qkv  = (const float*)d_in[1];
    const float* w_dw   = (const float*)d_in[2];
    const float* w_proj = (const float*)d_in[3];
    const float* temp   = (const float*)d_in[4];
    const float* a1     = (const float*)d_in[5];
    const float* a2     = (const float*)d_in[6];
    const float* a3     = (const float*)d_in[7];
    const float* a4     = (const float*)d_in[8];

    float* ws = (float*)d_ws;
    // region 0: qkv staging [B][768][HW] (25165824 floats); dead after dwconv,
    //           then reused for all small buffers.
    // region 1: dw output   [B][768][HW] (25165824 floats)
    float* qkv = ws;
    float* dw  = ws + (size_t)25165824;
    float* invn = ws;                        // 1024 floats
    float* part = ws + 4096;                 // 262144 floats
    float* attn = ws + 4096 + 262144;        // 16384 floats
    float* spar = attn + 16384;              // 16384 floats
    float* m2   = spar + 16384;              // 131072 floats

    // K1: qkv = W_qkv @ x
    gemm_k256<<<dim3(128, 12, 2), 256, 0, stream>>>(
        w_qkv, 0L, x, (long)DIMC * HW, qkv, (long)NCH * HW);
    // K2: depthwise 3x3
    dwconv3<<<dim3(16, NB * NCH), 256, 0, stream>>>(qkv, w_dw, dw);
    // K3: inverse norms of q,k rows
    l2norm_inv<<<NB * 512, 256, 0, stream>>>(dw, invn);
    // K4: Gram partials + reduce/scale
    gram_partial<<<dim3(16, 16), 256, 0, stream>>>(dw, part);
    gram_finish<<<64, 256, 0, stream>>>(part, invn, temp, attn);
    // K5: 4-way sparse softmax combine
    sparse_softmax<<<16, 1024, 0, stream>>>(attn, spar, a1, a2, a3, a4);
    // K6: fold proj @ spar into M2
    build_m2<<<512, 256, 0, stream>>>(w_proj, spar, m2);
    // K7: out = M2 @ v  (fp32 store to d_out)
    gemm_k256<<<dim3(128, 4, 2), 256, 0, stream>>>(
        m2, 65536L, dw + (size_t)512 * HW, (long)NCH * HW,
        (float*)d_out, (long)DIMC * HW);
}

// Round 4
// 276.774 us; speedup vs baseline: 1.3812x; 1.3812x over previous
//
#include <hip/hip_runtime.h>
#include <stdint.h>

// Problem geometry (fixed)
#define HW     16384      // 128*128
#define IMGW   128
#define NCH    768        // 3*DIM
#define DIMC   256
#define NB     2
#define CPH    32         // channels per head

typedef unsigned short u16;
typedef unsigned int   u32;
typedef __attribute__((ext_vector_type(8))) short bf16x8;
typedef __attribute__((ext_vector_type(4))) float f32x4;

__device__ __forceinline__ float bf2f(u16 u) { return __uint_as_float(((u32)u) << 16); }
__device__ __forceinline__ u16 f2bf(float f) {
    u32 u = __float_as_uint(f);
    u += 0x7fffu + ((u >> 16) & 1u);
    return (u16)(u >> 16);
}

#define GLOAD16(gp, lp) __builtin_amdgcn_global_load_lds( \
    (const __attribute__((address_space(1))) void*)(gp),  \
    (__attribute__((address_space(3))) void*)(lp), 16, 0, 0)

// ---------------------------------------------------------------------------
// T1: split W_qkv into hi/lo bf16, layout [s=8][768 m][32 c] with quad swizzle
//     slot u within 64B window holds true quad (u ^ ((m>>1)&3))
// ---------------------------------------------------------------------------
__global__ __launch_bounds__(256)
void wsplit(const float* __restrict__ w, u16* __restrict__ wh, u16* __restrict__ wl)
{
    const int idx = blockIdx.x * 256 + threadIdx.x;   // 0..6143
    const int m = idx >> 3, s = idx & 7;
    const int p = (m >> 1) & 3;
    #pragma unroll
    for (int u = 0; u < 4; ++u) {
        const int cb = s * 32 + ((u ^ p) << 3);
        u32 hq[4], lq[4];
        #pragma unroll
        for (int e2 = 0; e2 < 4; ++e2) {
            float f0 = w[m * 256 + cb + 2 * e2];
            float f1 = w[m * 256 + cb + 2 * e2 + 1];
            u16 h0 = f2bf(f0); u16 l0 = f2bf(f0 - bf2f(h0));
            u16 h1 = f2bf(f1); u16 l1 = f2bf(f1 - bf2f(h1));
            hq[e2] = (u32)h0 | ((u32)h1 << 16);
            lq[e2] = (u32)l0 | ((u32)l1 << 16);
        }
        size_t rowb = ((size_t)(s * 768 + m)) << 6;   // 64 B per row
        uint4 hv; hv.x = hq[0]; hv.y = hq[1]; hv.z = hq[2]; hv.w = hq[3];
        uint4 lv; lv.x = lq[0]; lv.y = lq[1]; lv.z = lq[2]; lv.w = lq[3];
        *(uint4*)((char*)wh + rowb + (u << 4)) = hv;
        *(uint4*)((char*)wl + rowb + (u << 4)) = lv;
    }
}

// ---------------------------------------------------------------------------
// T2: transpose + split x -> xT hi/lo bf16, layout [b*8+s][16384 n][32 c],
//     quad-swizzled per row: slot u holds true quad (u ^ ((n>>1)&3))
// grid: dim3(1024, 2): blockIdx.x = nt(0..255) | ct(0..3)<<8
// ---------------------------------------------------------------------------
__global__ __launch_bounds__(256)
void transp_split(const float* __restrict__ x, u16* __restrict__ xth, u16* __restrict__ xtl)
{
    __shared__ float Xs[64][68];
    const int bz = blockIdx.y;
    const int nt = blockIdx.x & 255;
    const int ct = blockIdx.x >> 8;
    const int n0 = nt * 64, c0 = ct * 64;
    const int t = threadIdx.x;
    const float* xb = x + (size_t)bz * DIMC * HW;

    #pragma unroll
    for (int it = 0; it < 4; ++it) {
        int cl = (t >> 4) + it * 16;
        int nl4 = (t & 15) << 2;
        float4 v = *(const float4*)(xb + (size_t)(c0 + cl) * HW + n0 + nl4);
        Xs[cl][nl4]     = v.x; Xs[cl][nl4 + 1] = v.y;
        Xs[cl][nl4 + 2] = v.z; Xs[cl][nl4 + 3] = v.w;
    }
    __syncthreads();

    const int nl = t >> 2, u = t & 3;
    const int p = (nl >> 1) & 3;                      // n0 is mult of 64
    #pragma unroll
    for (int sl = 0; sl < 2; ++sl) {
        const int s = (c0 >> 5) + sl;
        const int cb = sl * 32 + ((u ^ p) << 3);
        u32 hq[4], lq[4];
        #pragma unroll
        for (int e2 = 0; e2 < 4; ++e2) {
            float f0 = Xs[cb + 2 * e2][nl];
            float f1 = Xs[cb + 2 * e2 + 1][nl];
            u16 h0 = f2bf(f0); u16 l0 = f2bf(f0 - bf2f(h0));
            u16 h1 = f2bf(f1); u16 l1 = f2bf(f1 - bf2f(h1));
            hq[e2] = (u32)h0 | ((u32)h1 << 16);
            lq[e2] = (u32)l0 | ((u32)l1 << 16);
        }
        size_t rowb = ((size_t)((bz * 8 + s)) * 16384 + n0 + nl) << 6;
        uint4 hv; hv.x = hq[0]; hv.y = hq[1]; hv.z = hq[2]; hv.w = hq[3];
        uint4 lv; lv.x = lq[0]; lv.y = lq[1]; lv.z = lq[2]; lv.w = lq[3];
        *(uint4*)((char*)xth + rowb + (u << 4)) = hv;
        *(uint4*)((char*)xtl + rowb + (u << 4)) = lv;
    }
}

// ---------------------------------------------------------------------------
// K1': qkv[b][m][n] = sum_c W[m][c] * x[b][c][n] via split-bf16 MFMA.
// Tile 128m x 128n, BK=32, 4 waves (2x2), wave tile 64x64 = 4x4 frags 16x16.
// 3 products: Ah*Bh + Ah*Bl + Al*Bh  (fp32-equivalent precision)
// LDS 32 KB: Ah/Al/Bh/Bl each [128 rows][64 B], quad-swizzled (pre-baked).
// grid: dim3(6 mblk, 128 nblk, 2 b)
// ---------------------------------------------------------------------------
__global__ __launch_bounds__(256)
void gemm_mfma_split(const u16* __restrict__ whp, const u16* __restrict__ wlp,
                     const u16* __restrict__ xth, const u16* __restrict__ xtl,
                     float* __restrict__ qkv)
{
    __shared__ char smem[32768];   // Ah 0, Al 8192, Bh 16384, Bl 24576

    const int t    = threadIdx.x;
    const int lane = t & 63;
    const int w    = t >> 6;
    const int bz   = blockIdx.z;
    const int m0   = blockIdx.x * 128;
    const int n0   = blockIdx.y * 128;
    const int lrow  = lane >> 2;       // 0..15
    const int lquad = lane & 3;
    const int mh = w >> 1, nh = w & 1;
    // frag-read offset within a 16-row group: row (lane&15), swizzled quad
    const int swz = ((lane & 15) << 6) + ((((lane >> 4) ^ ((lane >> 1) & 3))) << 4);

    f32x4 acc[4][4];
    #pragma unroll
    for (int i = 0; i < 4; ++i)
        #pragma unroll
        for (int j = 0; j < 4; ++j)
            acc[i][j] = (f32x4){0.f, 0.f, 0.f, 0.f};

    for (int s = 0; s < 8; ++s) {
        // ---- stage 32 KB via global_load_lds (8 chunks of 1 KB per wave) ----
        #pragma unroll
        for (int i = 0; i < 8; ++i) {
            const int tile = i >> 1;                 // 0 Ah,1 Al,2 Bh,3 Bl
            const int r16  = ((i & 1) << 2) | w;     // 0..7
            char* dst = smem + tile * 8192 + r16 * 1024;
            const char* src;
            if (tile == 0)
                src = (const char*)whp + ((((size_t)s * 768) + m0 + r16 * 16 + lrow) << 6) + (lquad << 4);
            else if (tile == 1)
                src = (const char*)wlp + ((((size_t)s * 768) + m0 + r16 * 16 + lrow) << 6) + (lquad << 4);
            else if (tile == 2)
                src = (const char*)xth + ((((size_t)(bz * 8 + s)) * 16384 + n0 + r16 * 16 + lrow) << 6) + (lquad << 4);
            else
                src = (const char*)xtl + ((((size_t)(bz * 8 + s)) * 16384 + n0 + r16 * 16 + lrow) << 6) + (lquad << 4);
            GLOAD16(src, dst);
        }
        __syncthreads();   // compiler inserts vmcnt(0) drain before barrier

        // ---- fragment loads (conflict-free b128 via swizzle) ----
        bf16x8 ah[4], al[4], bh[4], bl[4];
        #pragma unroll
        for (int f = 0; f < 4; ++f) {
            const int aoff = (mh * 64 + f * 16) * 64 + swz;
            ah[f] = *(const bf16x8*)(smem + aoff);
            al[f] = *(const bf16x8*)(smem + 8192 + aoff);
            const int boff = (nh * 64 + f * 16) * 64 + swz;
            bh[f] = *(const bf16x8*)(smem + 16384 + boff);
            bl[f] = *(const bf16x8*)(smem + 24576 + boff);
        }

        // ---- 48 MFMAs: 16 frags x 3 split products ----
        #pragma unroll
        for (int fm = 0; fm < 4; ++fm)
            #pragma unroll
            for (int fn = 0; fn < 4; ++fn) {
                acc[fm][fn] = __builtin_amdgcn_mfma_f32_16x16x32_bf16(ah[fm], bh[fn], acc[fm][fn], 0, 0, 0);
                acc[fm][fn] = __builtin_amdgcn_mfma_f32_16x16x32_bf16(ah[fm], bl[fn], acc[fm][fn], 0, 0, 0);
                acc[fm][fn] = __builtin_amdgcn_mfma_f32_16x16x32_bf16(al[fm], bh[fn], acc[fm][fn], 0, 0, 0);
            }
        __syncthreads();
    }

    // ---- epilogue: C/D layout col=lane&15, row=(lane>>4)*4+reg (m89) ----
    float* Cb = qkv + (size_t)bz * NCH * HW;
    #pragma unroll
    for (int fm = 0; fm < 4; ++fm) {
        const int mrow0 = m0 + mh * 64 + fm * 16 + ((lane >> 4) << 2);
        #pragma unroll
        for (int fn = 0; fn < 4; ++fn) {
            const int ncol = n0 + nh * 64 + fn * 16 + (lane & 15);
            #pragma unroll
            for (int r = 0; r < 4; ++r)
                Cb[(size_t)(mrow0 + r) * HW + ncol] = acc[fm][fn][r];
        }
    }
}

// ---------------------------------------------------------------------------
// K2: depthwise 3x3 SAME (cross-correlation, per-channel weights)
// ---------------------------------------------------------------------------
__global__ __launch_bounds__(256)
void dwconv3(const float* __restrict__ in, const float* __restrict__ wdw,
             float* __restrict__ out)
{
    const int p  = blockIdx.y;                 // plane = bi*768 + ch
    const int t  = threadIdx.x;
    const int r  = blockIdx.x * 8 + (t >> 5);
    const int c0 = (t & 31) << 2;

    const float* plane = in + (size_t)p * HW;
    const float* wp = wdw + (p % NCH) * 9;
    float w[9];
    #pragma unroll
    for (int i = 0; i < 9; ++i) w[i] = wp[i];

    float acc[4] = {0.f, 0.f, 0.f, 0.f};
    #pragma unroll
    for (int dy = -1; dy <= 1; ++dy) {
        int ry = r + dy;
        if (ry < 0 || ry >= IMGW) continue;
        const float* rowp = plane + ry * IMGW;
        float4 vm = *reinterpret_cast<const float4*>(rowp + c0);
        float vl = (c0 > 0)   ? rowp[c0 - 1] : 0.f;
        float vr = (c0 < 124) ? rowp[c0 + 4] : 0.f;
        float vals[6] = {vl, vm.x, vm.y, vm.z, vm.w, vr};
        int wr = (dy + 1) * 3;
        #pragma unroll
        for (int dx = 0; dx < 3; ++dx) {
            float wv = w[wr + dx];
            #pragma unroll
            for (int q = 0; q < 4; ++q)
                acc[q] = fmaf(vals[q + dx], wv, acc[q]);
        }
    }
    float4 o4 = {acc[0], acc[1], acc[2], acc[3]};
    *reinterpret_cast<float4*>(out + (size_t)p * HW + r * IMGW + c0) = o4;
}

// ---------------------------------------------------------------------------
// K3: inverse l2 norms of q,k rows. grid = B*512 blocks (one per row)
// ---------------------------------------------------------------------------
__global__ __launch_bounds__(256)
void l2norm_inv(const float* __restrict__ dw, float* __restrict__ invn)
{
    const int idx = blockIdx.x;          // 0..1023
    const int bi  = idx >> 9;
    const int ch  = idx & 511;           // q: 0..255, k: 256..511
    const float* row = dw + ((size_t)bi * NCH + ch) * HW;

    float s = 0.f;
    for (int i = threadIdx.x; i < HW / 4; i += 256) {
        float4 v = reinterpret_cast<const float4*>(row)[i];
        s = fmaf(v.x, v.x, s); s = fmaf(v.y, v.y, s);
        s = fmaf(v.z, v.z, s); s = fmaf(v.w, v.w, s);
    }
    #pragma unroll
    for (int off = 32; off; off >>= 1) s += __shfl_down(s, off);
    __shared__ float red[4];
    if ((threadIdx.x & 63) == 0) red[threadIdx.x >> 6] = s;
    __syncthreads();
    if (threadIdx.x == 0) {
        float tot = red[0] + red[1] + red[2] + red[3];
        invn[idx] = 1.f / fmaxf(sqrtf(tot), 1e-12f);
    }
}

// ---------------------------------------------------------------------------
// K4: Gram partials. grid (16 n-chunks, 16 bh). part: [chunk][bh][32*32]
// ---------------------------------------------------------------------------
__global__ __launch_bounds__(256)
void gram_partial(const float* __restrict__ dw, float* __restrict__ part)
{
    __shared__ float Qs[32][132];
    __shared__ float Ks[32][132];
    const int chunk = blockIdx.x;
    const int bh    = blockIdx.y;
    const int bi = bh >> 3, h = bh & 7;
    const float* qbase = dw + ((size_t)bi * NCH + h * CPH) * HW;
    const float* kbase = dw + ((size_t)bi * NCH + 256 + h * CPH) * HW;
    const int t = threadIdx.x;
    const int c = t >> 3, d0 = (t & 7) << 2;

    float acc[4] = {0.f, 0.f, 0.f, 0.f};
    for (int sub = 0; sub < 8; ++sub) {
        int nbase = chunk * 1024 + sub * 128;
        __syncthreads();
        #pragma unroll
        for (int r = 0; r < 4; ++r) {
            int idx = t + r * 256;
            int row = idx >> 5, col = (idx & 31) << 2;
            *reinterpret_cast<float4*>(&Qs[row][col]) =
                *reinterpret_cast<const float4*>(qbase + (size_t)row * HW + nbase + col);
            *reinterpret_cast<float4*>(&Ks[row][col]) =
                *reinterpret_cast<const float4*>(kbase + (size_t)row * HW + nbase + col);
        }
        __syncthreads();
        #pragma unroll 8
        for (int n4 = 0; n4 < 32; ++n4) {
            float4 q4 = *reinterpret_cast<const float4*>(&Qs[c][n4 << 2]);
            #pragma unroll
            for (int j = 0; j < 4; ++j) {
                float4 k4 = *reinterpret_cast<const float4*>(&Ks[d0 + j][n4 << 2]);
                acc[j] = fmaf(q4.x, k4.x, acc[j]);
                acc[j] = fmaf(q4.y, k4.y, acc[j]);
                acc[j] = fmaf(q4.z, k4.z, acc[j]);
                acc[j] = fmaf(q4.w, k4.w, acc[j]);
            }
        }
    }
    float4 o4 = {acc[0], acc[1], acc[2], acc[3]};
    *reinterpret_cast<float4*>(part + ((size_t)chunk * 16 + bh) * 1024 + c * 32 + d0) = o4;
}

// ---------------------------------------------------------------------------
// K4b: reduce partials + apply inv norms and temperature
// ---------------------------------------------------------------------------
__global__ __launch_bounds__(256)
void gram_finish(const float* __restrict__ part, const float* __restrict__ invn,
                 const float* __restrict__ temp, float* __restrict__ attn)
{
    const int idx = blockIdx.x * 256 + threadIdx.x;  // 0..16383
    const int bh = idx >> 10;
    const int bi = bh >> 3, h = bh & 7;
    const int c = (idx >> 5) & 31, d = idx & 31;
    float s = 0.f;
    #pragma unroll
    for (int ch = 0; ch < 16; ++ch) s += part[(size_t)ch * 16384 + idx];
    float iq = invn[bi * 512 + h * CPH + c];
    float ik = invn[bi * 512 + 256 + h * CPH + d];
    attn[idx] = s * iq * ik * temp[h];
}

// ---------------------------------------------------------------------------
// K5: rank-based 4-way sparse softmax combine. One block (1024 thr) per bh.
// ---------------------------------------------------------------------------
__global__ __launch_bounds__(1024)
void sparse_softmax(const float* __restrict__ attn, float* __restrict__ spar,
                    const float* __restrict__ a1, const float* __restrict__ a2,
                    const float* __restrict__ a3, const float* __restrict__ a4)
{
    __shared__ float xs[1024];
    __shared__ float red[16 * 4];
    __shared__ float vthr[4];
    __shared__ float msh;
    __shared__ float ssh[4];

    const int bh = blockIdx.x, t = threadIdx.x;
    float x = attn[bh * 1024 + t];
    xs[t] = x;
    __syncthreads();

    int g = 0, e = 0;
    for (int j = 0; j < 1024; ++j) {
        float v = xs[j];
        g += (v > x);
        e += (v == x);
    }
    if (g == 0) msh = x;  // all writers hold the identical max value
    const int topks[4] = {512, 682, 768, 819};
    #pragma unroll
    for (int kk = 0; kk < 4; ++kk)
        if (g <= topks[kk] - 1 && topks[kk] - 1 < g + e) vthr[kk] = x;  // rank-(topk-1) value
    __syncthreads();

    float m  = msh;
    float ex = expf(x - m);
    float v4[4];
    #pragma unroll
    for (int kk = 0; kk < 4; ++kk) v4[kk] = (x >= vthr[kk]) ? ex : 0.f;
    #pragma unroll
    for (int off = 32; off; off >>= 1)
        #pragma unroll
        for (int kk = 0; kk < 4; ++kk) v4[kk] += __shfl_down(v4[kk], off);
    const int lane = t & 63, wid = t >> 6;
    if (lane == 0) {
        #pragma unroll
        for (int kk = 0; kk < 4; ++kk) red[wid * 4 + kk] = v4[kk];
    }
    __syncthreads();
    if (t == 0) {
        float s0 = 0, s1 = 0, s2 = 0, s3 = 0;
        for (int w = 0; w < 16; ++w) {
            s0 += red[w * 4 + 0]; s1 += red[w * 4 + 1];
            s2 += red[w * 4 + 2]; s3 += red[w * 4 + 3];
        }
        ssh[0] = s0; ssh[1] = s1; ssh[2] = s2; ssh[3] = s3;
    }
    __syncthreads();

    float av[4] = {*a1, *a2, *a3, *a4};
    float coef = 0.f;
    #pragma unroll
    for (int kk = 0; kk < 4; ++kk)
        if (x >= vthr[kk]) coef += av[kk] / ssh[kk];
    spar[bh * 1024 + t] = ex * coef;
}

// ---------------------------------------------------------------------------
// K6: M2[b][o][h*32+d] = sum_cc Wproj[o][h*32+cc] * spar[b,h,cc,d]
// ---------------------------------------------------------------------------
__global__ __launch_bounds__(256)
void build_m2(const float* __restrict__ wproj, const float* __restrict__ spar,
              float* __restrict__ m2)
{
    const int idx = blockIdx.x * 256 + threadIdx.x;  // 0..131071
    const int b = idx >> 16, o = (idx >> 8) & 255, hd = idx & 255;
    const int h = hd >> 5, d = hd & 31;
    const float* wrow = wproj + o * 256 + h * CPH;
    const float* sp = spar + (size_t)(b * 8 + h) * 1024 + d;
    float acc = 0.f;
    #pragma unroll 8
    for (int cc = 0; cc < 32; ++cc)
        acc = fmaf(wrow[cc], sp[cc * 32], acc);
    m2[idx] = acc;
}

// ---------------------------------------------------------------------------
// K7: C[M,HW] = A[M,256] * B[256,HW]  fp32 (out = M2 @ v)
// ---------------------------------------------------------------------------
__global__ __launch_bounds__(256)
void gemm_k256(const float* __restrict__ A, long aStride,
               const float* __restrict__ Bm, long bStride,
               float* __restrict__ Cm, long cStride)
{
    __shared__ float As[16][68];    // [k][m], padded
    __shared__ float Bs[16][132];   // [k][n], padded

    const int t  = threadIdx.x;
    const int bz = blockIdx.z;
    const int m0 = blockIdx.y * 64;
    const int n0 = blockIdx.x * 128;

    const float* Ab = A  + (size_t)bz * aStride;
    const float* Bb = Bm + (size_t)bz * bStride;

    const int ty = t >> 4, tx = t & 15;
    const int mb = ty * 4, nb = tx * 8;

    float acc[4][8];
    #pragma unroll
    for (int i = 0; i < 4; ++i)
        #pragma unroll
        for (int j = 0; j < 8; ++j) acc[i][j] = 0.f;

    const int a_m = t >> 2;            // 0..63
    const int a_k = (t & 3) << 2;      // 0,4,8,12

    for (int k0 = 0; k0 < 256; k0 += 16) {
        __syncthreads();
        float4 a4 = *reinterpret_cast<const float4*>(Ab + (size_t)(m0 + a_m) * 256 + k0 + a_k);
        As[a_k + 0][a_m] = a4.x;
        As[a_k + 1][a_m] = a4.y;
        As[a_k + 2][a_m] = a4.z;
        As[a_k + 3][a_m] = a4.w;
        #pragma unroll
        for (int r = 0; r < 2; ++r) {
            int idx = t + r * 256;
            int br = idx >> 5, bc = (idx & 31) << 2;
            *reinterpret_cast<float4*>(&Bs[br][bc]) =
                *reinterpret_cast<const float4*>(Bb + (size_t)(k0 + br) * HW + n0 + bc);
        }
        __syncthreads();
        #pragma unroll
        for (int kk = 0; kk < 16; ++kk) {
            float4 av  = *reinterpret_cast<const float4*>(&As[kk][mb]);
            float4 bv0 = *reinterpret_cast<const float4*>(&Bs[kk][nb]);
            float4 bv1 = *reinterpret_cast<const float4*>(&Bs[kk][nb + 4]);
            float ae[4] = {av.x, av.y, av.z, av.w};
            float be[8] = {bv0.x, bv0.y, bv0.z, bv0.w, bv1.x, bv1.y, bv1.z, bv1.w};
            #pragma unroll
            for (int i = 0; i < 4; ++i)
                #pragma unroll
                for (int j = 0; j < 8; ++j)
                    acc[i][j] = fmaf(ae[i], be[j], acc[i][j]);
        }
    }

    #pragma unroll
    for (int i = 0; i < 4; ++i) {
        float4 lo = {acc[i][0], acc[i][1], acc[i][2], acc[i][3]};
        float4 hi = {acc[i][4], acc[i][5], acc[i][6], acc[i][7]};
        float* p = Cm + (size_t)bz * cStride + (size_t)(m0 + mb + i) * HW + n0 + nb;
        *reinterpret_cast<float4*>(p)     = lo;
        *reinterpret_cast<float4*>(p + 4) = hi;
    }
}

// ---------------------------------------------------------------------------
// launch
// ---------------------------------------------------------------------------
extern "C" void kernel_launch(void* const* d_in, const int* in_sizes, int n_in,
                              void* d_out, int out_size, void* d_ws, size_t ws_size,
                              hipStream_t stream)
{
    const float* x      = (const float*)d_in[0];
    const float* w_qkv  = (const float*)d_in[1];
    const float* w_dw   = (const float*)d_in[2];
    const float* w_proj = (const float*)d_in[3];
    const float* temp   = (const float*)d_in[4];
    const float* a1     = (const float*)d_in[5];
    const float* a2     = (const float*)d_in[6];
    const float* a3     = (const float*)d_in[7];
    const float* a4     = (const float*)d_in[8];

    float* ws = (float*)d_ws;
    // region 0: qkv [B][768][HW] fp32 (25165824 f); dead after dwconv, then
    //           reused for invn/part/attn/spar/m2.
    // region 1: dw  [B][768][HW] fp32 (25165824 f); its head holds xT/wh/wl
    //           during T1/T2/K1' (dead before dwconv writes region 1).
    float* qkv = ws;
    float* dwp = ws + (size_t)25165824;
    u16* xth = (u16*)dwp;                    // 2*8*16384*32 = 8388608 bf16
    u16* xtl = xth + (size_t)8388608;
    u16* whp = xtl + (size_t)8388608;        // 8*768*32 = 196608 bf16
    u16* wlp = whp + (size_t)196608;
    float* invn = ws;                        // 1024 floats
    float* part = ws + 4096;                 // 262144 floats
    float* attn = ws + 4096 + 262144;        // 16384 floats
    float* spar = attn + 16384;              // 16384 floats
    float* m2   = spar + 16384;              // 131072 floats

    // T1/T2: split W, transpose+split x (both pre-swizzled for LDS banks)
    wsplit<<<24, 256, 0, stream>>>(w_qkv, whp, wlp);
    transp_split<<<dim3(1024, 2), 256, 0, stream>>>(x, xth, xtl);
    // K1': qkv = W_qkv @ x via split-bf16 MFMA
    gemm_mfma_split<<<dim3(6, 128, 2), 256, 0, stream>>>(whp, wlp, xth, xtl, qkv);
    // K2: depthwise 3x3
    dwconv3<<<dim3(16, NB * NCH), 256, 0, stream>>>(qkv, w_dw, dwp);
    // K3: inverse norms of q,k rows
    l2norm_inv<<<NB * 512, 256, 0, stream>>>(dwp, invn);
    // K4: Gram partials + reduce/scale
    gram_partial<<<dim3(16, 16), 256, 0, stream>>>(dwp, part);
    gram_finish<<<64, 256, 0, stream>>>(part, invn, temp, attn);
    // K5: 4-way sparse softmax combine
    sparse_softmax<<<16, 1024, 0, stream>>>(attn, spar, a1, a2, a3, a4);
    // K6: fold proj @ spar into M2
    build_m2<<<512, 256, 0, stream>>>(w_proj, spar, m2);
    // K7: out = M2 @ v  (fp32)
    gemm_k256<<<dim3(128, 4, 2), 256, 0, stream>>>(
        m2, 65536L, dwp + (size_t)512 * HW, (long)NCH * HW,
        (float*)d_out, (long)DIMC * HW);
}

// Round 5
// 234.797 us; speedup vs baseline: 1.6282x; 1.1788x over previous
//
#include <hip/hip_runtime.h>
#include <stdint.h>

// Problem geometry (fixed)
#define HW     16384      // 128*128
#define IMGW   128
#define NCH    768        // 3*DIM
#define DIMC   256
#define NB     2
#define CPH    32         // channels per head

typedef unsigned short u16;
typedef unsigned int   u32;
typedef __attribute__((ext_vector_type(8))) short bf16x8;
typedef __attribute__((ext_vector_type(4))) float f32x4;

__device__ __forceinline__ float bf2f(u16 u) { return __uint_as_float(((u32)u) << 16); }
__device__ __forceinline__ u16 f2bf(float f) {
    u32 u = __float_as_uint(f);
    u += 0x7fffu + ((u >> 16) & 1u);
    return (u16)(u >> 16);
}

#define GLOAD16(gp, lp) __builtin_amdgcn_global_load_lds( \
    (const __attribute__((address_space(1))) void*)(gp),  \
    (__attribute__((address_space(3))) void*)(lp), 16, 0, 0)

// ---------------------------------------------------------------------------
// T1: split W_qkv into hi/lo bf16, layout [s=8][768 m][32 c] with quad swizzle
//     slot u within 64B window holds true quad (u ^ ((m>>1)&3))
// ---------------------------------------------------------------------------
__global__ __launch_bounds__(256)
void wsplit(const float* __restrict__ w, u16* __restrict__ wh, u16* __restrict__ wl)
{
    const int idx = blockIdx.x * 256 + threadIdx.x;   // 0..6143
    const int m = idx >> 3, s = idx & 7;
    const int p = (m >> 1) & 3;
    #pragma unroll
    for (int u = 0; u < 4; ++u) {
        const int cb = s * 32 + ((u ^ p) << 3);
        u32 hq[4], lq[4];
        #pragma unroll
        for (int e2 = 0; e2 < 4; ++e2) {
            float f0 = w[m * 256 + cb + 2 * e2];
            float f1 = w[m * 256 + cb + 2 * e2 + 1];
            u16 h0 = f2bf(f0); u16 l0 = f2bf(f0 - bf2f(h0));
            u16 h1 = f2bf(f1); u16 l1 = f2bf(f1 - bf2f(h1));
            hq[e2] = (u32)h0 | ((u32)h1 << 16);
            lq[e2] = (u32)l0 | ((u32)l1 << 16);
        }
        size_t rowb = ((size_t)(s * 768 + m)) << 6;   // 64 B per row
        uint4 hv; hv.x = hq[0]; hv.y = hq[1]; hv.z = hq[2]; hv.w = hq[3];
        uint4 lv; lv.x = lq[0]; lv.y = lq[1]; lv.z = lq[2]; lv.w = lq[3];
        *(uint4*)((char*)wh + rowb + (u << 4)) = hv;
        *(uint4*)((char*)wl + rowb + (u << 4)) = lv;
    }
}

// ---------------------------------------------------------------------------
// T2/T3: transpose + split src[bz][256 c][HW n] -> hi/lo bf16
// dst layout [b*8+s][16384 n][32 c], quad-swizzled: slot u holds quad u^((n>>1)&3)
// grid: dim3(1024, 2): blockIdx.x = nt(0..255) | ct(0..3)<<8
// ---------------------------------------------------------------------------
__global__ __launch_bounds__(256)
void transp_split(const float* __restrict__ src, long srcBatch,
                  u16* __restrict__ dsth, u16* __restrict__ dstl)
{
    __shared__ float Xs[64][68];
    const int bz = blockIdx.y;
    const int nt = blockIdx.x & 255;
    const int ct = blockIdx.x >> 8;
    const int n0 = nt * 64, c0 = ct * 64;
    const int t = threadIdx.x;
    const float* xb = src + (size_t)bz * srcBatch;

    #pragma unroll
    for (int it = 0; it < 4; ++it) {
        int cl = (t >> 4) + it * 16;
        int nl4 = (t & 15) << 2;
        float4 v = *(const float4*)(xb + (size_t)(c0 + cl) * HW + n0 + nl4);
        Xs[cl][nl4]     = v.x; Xs[cl][nl4 + 1] = v.y;
        Xs[cl][nl4 + 2] = v.z; Xs[cl][nl4 + 3] = v.w;
    }
    __syncthreads();

    const int nl = t >> 2, u = t & 3;
    const int p = (nl >> 1) & 3;                      // n0 is mult of 64
    #pragma unroll
    for (int sl = 0; sl < 2; ++sl) {
        const int s = (c0 >> 5) + sl;
        const int cb = sl * 32 + ((u ^ p) << 3);
        u32 hq[4], lq[4];
        #pragma unroll
        for (int e2 = 0; e2 < 4; ++e2) {
            float f0 = Xs[cb + 2 * e2][nl];
            float f1 = Xs[cb + 2 * e2 + 1][nl];
            u16 h0 = f2bf(f0); u16 l0 = f2bf(f0 - bf2f(h0));
            u16 h1 = f2bf(f1); u16 l1 = f2bf(f1 - bf2f(h1));
            hq[e2] = (u32)h0 | ((u32)h1 << 16);
            lq[e2] = (u32)l0 | ((u32)l1 << 16);
        }
        size_t rowb = ((size_t)((bz * 8 + s)) * 16384 + n0 + nl) << 6;
        uint4 hv; hv.x = hq[0]; hv.y = hq[1]; hv.z = hq[2]; hv.w = hq[3];
        uint4 lv; lv.x = lq[0]; lv.y = lq[1]; lv.z = lq[2]; lv.w = lq[3];
        *(uint4*)((char*)dsth + rowb + (u << 4)) = hv;
        *(uint4*)((char*)dstl + rowb + (u << 4)) = lv;
    }
}

// ---------------------------------------------------------------------------
// K1'/K7': C[bz][m][n] = sum_c A[m][c] * B[bz][c][n] via split-bf16 MFMA.
// Tile 128m x 128n, K=256 (8 slices of 32), 4 waves (2x2), wave tile 64x64.
// 3 products: Ah*Bh + Ah*Bl + Al*Bh  (fp32-equivalent precision)
// A row index = bz*aBatch + s*aSlice + m;  B row = (bz*8+s)*16384 + n
// LDS 32 KB: Ah/Al/Bh/Bl each [128 rows][64 B], quad-swizzled (pre-baked).
// ---------------------------------------------------------------------------
__global__ __launch_bounds__(256)
void gemm_mfma_split(const u16* __restrict__ Ahp, const u16* __restrict__ Alp,
                     const u16* __restrict__ Bhp, const u16* __restrict__ Blp,
                     float* __restrict__ Cp, int aBatch, int aSlice, long cBatch)
{
    __shared__ char smem[32768];   // Ah 0, Al 8192, Bh 16384, Bl 24576

    const int t    = threadIdx.x;
    const int lane = t & 63;
    const int w    = t >> 6;
    const int bz   = blockIdx.z;
    const int m0   = blockIdx.x * 128;
    const int n0   = blockIdx.y * 128;
    const int lrow  = lane >> 2;       // 0..15
    const int lquad = lane & 3;
    const int mh = w >> 1, nh = w & 1;
    // frag-read offset within a 16-row group: row (lane&15), swizzled quad
    const int swz = ((lane & 15) << 6) + ((((lane >> 4) ^ ((lane >> 1) & 3))) << 4);

    f32x4 acc[4][4];
    #pragma unroll
    for (int i = 0; i < 4; ++i)
        #pragma unroll
        for (int j = 0; j < 4; ++j)
            acc[i][j] = (f32x4){0.f, 0.f, 0.f, 0.f};

    for (int s = 0; s < 8; ++s) {
        const size_t arow0 = (size_t)bz * aBatch + (size_t)s * aSlice + m0;
        const size_t brow0 = ((size_t)(bz * 8 + s)) * 16384 + n0;
        // ---- stage 32 KB via global_load_lds (8 chunks of 1 KB per wave) ----
        #pragma unroll
        for (int i = 0; i < 8; ++i) {
            const int tile = i >> 1;                 // 0 Ah,1 Al,2 Bh,3 Bl
            const int r16  = ((i & 1) << 2) | w;     // 0..7
            char* dst = smem + tile * 8192 + r16 * 1024;
            const char* src;
            if (tile == 0)
                src = (const char*)Ahp + ((arow0 + r16 * 16 + lrow) << 6) + (lquad << 4);
            else if (tile == 1)
                src = (const char*)Alp + ((arow0 + r16 * 16 + lrow) << 6) + (lquad << 4);
            else if (tile == 2)
                src = (const char*)Bhp + ((brow0 + r16 * 16 + lrow) << 6) + (lquad << 4);
            else
                src = (const char*)Blp + ((brow0 + r16 * 16 + lrow) << 6) + (lquad << 4);
            GLOAD16(src, dst);
        }
        __syncthreads();   // compiler inserts vmcnt(0) drain before barrier

        // ---- fragment loads (conflict-free b128 via swizzle) ----
        bf16x8 ah[4], al[4], bh[4], bl[4];
        #pragma unroll
        for (int f = 0; f < 4; ++f) {
            const int aoff = (mh * 64 + f * 16) * 64 + swz;
            ah[f] = *(const bf16x8*)(smem + aoff);
            al[f] = *(const bf16x8*)(smem + 8192 + aoff);
            const int boff = (nh * 64 + f * 16) * 64 + swz;
            bh[f] = *(const bf16x8*)(smem + 16384 + boff);
            bl[f] = *(const bf16x8*)(smem + 24576 + boff);
        }

        // ---- 48 MFMAs: 16 frags x 3 split products ----
        #pragma unroll
        for (int fm = 0; fm < 4; ++fm)
            #pragma unroll
            for (int fn = 0; fn < 4; ++fn) {
                acc[fm][fn] = __builtin_amdgcn_mfma_f32_16x16x32_bf16(ah[fm], bh[fn], acc[fm][fn], 0, 0, 0);
                acc[fm][fn] = __builtin_amdgcn_mfma_f32_16x16x32_bf16(ah[fm], bl[fn], acc[fm][fn], 0, 0, 0);
                acc[fm][fn] = __builtin_amdgcn_mfma_f32_16x16x32_bf16(al[fm], bh[fn], acc[fm][fn], 0, 0, 0);
            }
        __syncthreads();
    }

    // ---- epilogue: C/D layout col=lane&15, row=(lane>>4)*4+reg (m89) ----
    float* Cb = Cp + (size_t)bz * cBatch;
    #pragma unroll
    for (int fm = 0; fm < 4; ++fm) {
        const int mrow0 = m0 + mh * 64 + fm * 16 + ((lane >> 4) << 2);
        #pragma unroll
        for (int fn = 0; fn < 4; ++fn) {
            const int ncol = n0 + nh * 64 + fn * 16 + (lane & 15);
            #pragma unroll
            for (int r = 0; r < 4; ++r)
                Cb[(size_t)(mrow0 + r) * HW + ncol] = acc[fm][fn][r];
        }
    }
}

// ---------------------------------------------------------------------------
// K2: depthwise 3x3 SAME (cross-correlation, per-channel weights)
// ---------------------------------------------------------------------------
__global__ __launch_bounds__(256)
void dwconv3(const float* __restrict__ in, const float* __restrict__ wdw,
             float* __restrict__ out)
{
    const int p  = blockIdx.y;                 // plane = bi*768 + ch
    const int t  = threadIdx.x;
    const int r  = blockIdx.x * 8 + (t >> 5);
    const int c0 = (t & 31) << 2;

    const float* plane = in + (size_t)p * HW;
    const float* wp = wdw + (p % NCH) * 9;
    float w[9];
    #pragma unroll
    for (int i = 0; i < 9; ++i) w[i] = wp[i];

    float acc[4] = {0.f, 0.f, 0.f, 0.f};
    #pragma unroll
    for (int dy = -1; dy <= 1; ++dy) {
        int ry = r + dy;
        if (ry < 0 || ry >= IMGW) continue;
        const float* rowp = plane + ry * IMGW;
        float4 vm = *reinterpret_cast<const float4*>(rowp + c0);
        float vl = (c0 > 0)   ? rowp[c0 - 1] : 0.f;
        float vr = (c0 < 124) ? rowp[c0 + 4] : 0.f;
        float vals[6] = {vl, vm.x, vm.y, vm.z, vm.w, vr};
        int wr = (dy + 1) * 3;
        #pragma unroll
        for (int dx = 0; dx < 3; ++dx) {
            float wv = w[wr + dx];
            #pragma unroll
            for (int q = 0; q < 4; ++q)
                acc[q] = fmaf(vals[q + dx], wv, acc[q]);
        }
    }
    float4 o4 = {acc[0], acc[1], acc[2], acc[3]};
    *reinterpret_cast<float4*>(out + (size_t)p * HW + r * IMGW + c0) = o4;
}

// ---------------------------------------------------------------------------
// K4: Gram partials + per-channel sumsq partials (l2norm fused in).
// grid (16 n-chunks, 16 bh). part: [chunk][bh][32*32]; sumsqp: [chunk][bh][64]
// ---------------------------------------------------------------------------
__global__ __launch_bounds__(256)
void gram_partial(const float* __restrict__ dw, float* __restrict__ part,
                  float* __restrict__ sumsqp)
{
    __shared__ float Qs[32][132];
    __shared__ float Ks[32][132];
    const int chunk = blockIdx.x;
    const int bh    = blockIdx.y;
    const int bi = bh >> 3, h = bh & 7;
    const float* qbase = dw + ((size_t)bi * NCH + h * CPH) * HW;
    const float* kbase = dw + ((size_t)bi * NCH + 256 + h * CPH) * HW;
    const int t = threadIdx.x;
    const int c = t >> 3, d0 = (t & 7) << 2;
    const int ch64 = t >> 2;          // 0..63 (0..31 q, 32..63 k)
    const int qtr  = t & 3;

    float acc[4] = {0.f, 0.f, 0.f, 0.f};
    float sq = 0.f;
    for (int sub = 0; sub < 8; ++sub) {
        int nbase = chunk * 1024 + sub * 128;
        __syncthreads();
        #pragma unroll
        for (int r = 0; r < 4; ++r) {
            int idx = t + r * 256;
            int row = idx >> 5, col = (idx & 31) << 2;
            *reinterpret_cast<float4*>(&Qs[row][col]) =
                *reinterpret_cast<const float4*>(qbase + (size_t)row * HW + nbase + col);
            *reinterpret_cast<float4*>(&Ks[row][col]) =
                *reinterpret_cast<const float4*>(kbase + (size_t)row * HW + nbase + col);
        }
        __syncthreads();
        #pragma unroll 8
        for (int n4 = 0; n4 < 32; ++n4) {
            float4 q4 = *reinterpret_cast<const float4*>(&Qs[c][n4 << 2]);
            #pragma unroll
            for (int j = 0; j < 4; ++j) {
                float4 k4 = *reinterpret_cast<const float4*>(&Ks[d0 + j][n4 << 2]);
                acc[j] = fmaf(q4.x, k4.x, acc[j]);
                acc[j] = fmaf(q4.y, k4.y, acc[j]);
                acc[j] = fmaf(q4.z, k4.z, acc[j]);
                acc[j] = fmaf(q4.w, k4.w, acc[j]);
            }
        }
        // fused sumsq: thread covers (ch64, quarter), stride-4 stagger keeps
        // the 4 quarter-lanes on distinct banks (132%32=4 -> bank 4c+qtr+4i)
        {
            const float* srow = (ch64 < 32) ? &Qs[ch64][0] : &Ks[ch64 - 32][0];
            #pragma unroll 8
            for (int i = 0; i < 32; ++i) {
                float v = srow[qtr + 4 * i];
                sq = fmaf(v, v, sq);
            }
        }
    }
    // reduce quarters (adjacent lanes within wave)
    sq += __shfl_xor(sq, 1);
    sq += __shfl_xor(sq, 2);
    if (qtr == 0) sumsqp[((size_t)chunk * 16 + bh) * 64 + ch64] = sq;

    float4 o4 = {acc[0], acc[1], acc[2], acc[3]};
    *reinterpret_cast<float4*>(part + ((size_t)chunk * 16 + bh) * 1024 + c * 32 + d0) = o4;
}

// ---------------------------------------------------------------------------
// K4b: reduce partials + apply inv norms (from sumsq partials) and temperature
// ---------------------------------------------------------------------------
__global__ __launch_bounds__(256)
void gram_finish(const float* __restrict__ part, const float* __restrict__ sumsqp,
                 const float* __restrict__ temp, float* __restrict__ attn)
{
    const int idx = blockIdx.x * 256 + threadIdx.x;  // 0..16383
    const int bh = idx >> 10;
    const int h = bh & 7;
    const int c = (idx >> 5) & 31, d = idx & 31;
    float s = 0.f, sqq = 0.f, sqk = 0.f;
    #pragma unroll
    for (int ch = 0; ch < 16; ++ch) {
        s   += part[(size_t)ch * 16384 + idx];
        sqq += sumsqp[((size_t)ch * 16 + bh) * 64 + c];
        sqk += sumsqp[((size_t)ch * 16 + bh) * 64 + 32 + d];
    }
    float iq = 1.f / fmaxf(sqrtf(sqq), 1e-12f);
    float ik = 1.f / fmaxf(sqrtf(sqk), 1e-12f);
    attn[idx] = s * iq * ik * temp[h];
}

// ---------------------------------------------------------------------------
// K5: rank-based 4-way sparse softmax combine. One block (1024 thr) per bh.
// ---------------------------------------------------------------------------
__global__ __launch_bounds__(1024)
void sparse_softmax(const float* __restrict__ attn, float* __restrict__ spar,
                    const float* __restrict__ a1, const float* __restrict__ a2,
                    const float* __restrict__ a3, const float* __restrict__ a4)
{
    __shared__ float xs[1024];
    __shared__ float red[16 * 4];
    __shared__ float vthr[4];
    __shared__ float msh;
    __shared__ float ssh[4];

    const int bh = blockIdx.x, t = threadIdx.x;
    float x = attn[bh * 1024 + t];
    xs[t] = x;
    __syncthreads();

    int g = 0, e = 0;
    for (int j = 0; j < 1024; ++j) {
        float v = xs[j];
        g += (v > x);
        e += (v == x);
    }
    if (g == 0) msh = x;  // all writers hold the identical max value
    const int topks[4] = {512, 682, 768, 819};
    #pragma unroll
    for (int kk = 0; kk < 4; ++kk)
        if (g <= topks[kk] - 1 && topks[kk] - 1 < g + e) vthr[kk] = x;  // rank-(topk-1) value
    __syncthreads();

    float m  = msh;
    float ex = expf(x - m);
    float v4[4];
    #pragma unroll
    for (int kk = 0; kk < 4; ++kk) v4[kk] = (x >= vthr[kk]) ? ex : 0.f;
    #pragma unroll
    for (int off = 32; off; off >>= 1)
        #pragma unroll
        for (int kk = 0; kk < 4; ++kk) v4[kk] += __shfl_down(v4[kk], off);
    const int lane = t & 63, wid = t >> 6;
    if (lane == 0) {
        #pragma unroll
        for (int kk = 0; kk < 4; ++kk) red[wid * 4 + kk] = v4[kk];
    }
    __syncthreads();
    if (t == 0) {
        float s0 = 0, s1 = 0, s2 = 0, s3 = 0;
        for (int w = 0; w < 16; ++w) {
            s0 += red[w * 4 + 0]; s1 += red[w * 4 + 1];
            s2 += red[w * 4 + 2]; s3 += red[w * 4 + 3];
        }
        ssh[0] = s0; ssh[1] = s1; ssh[2] = s2; ssh[3] = s3;
    }
    __syncthreads();

    float av[4] = {*a1, *a2, *a3, *a4};
    float coef = 0.f;
    #pragma unroll
    for (int kk = 0; kk < 4; ++kk)
        if (x >= vthr[kk]) coef += av[kk] / ssh[kk];
    spar[bh * 1024 + t] = ex * coef;
}

// ---------------------------------------------------------------------------
// K6: M2[b][o][hd] = sum_cc Wproj[o][h*32+cc]*spar[b,h,cc,d]; emit split bf16
// in MFMA A-layout: row = b*2048 + s*256 + o (s=hd>>5), 32 c-slots quad-swizzled
// ---------------------------------------------------------------------------
__global__ __launch_bounds__(256)
void build_m2_split(const float* __restrict__ wproj, const float* __restrict__ spar,
                    u16* __restrict__ m2h, u16* __restrict__ m2l)
{
    const int idx = blockIdx.x * 256 + threadIdx.x;  // 0..131071
    const int b = idx >> 16, o = (idx >> 8) & 255, hd = idx & 255;
    const int h = hd >> 5, d = hd & 31;
    const float* wrow = wproj + o * 256 + h * CPH;
    const float* sp = spar + (size_t)(b * 8 + h) * 1024 + d;
    float acc = 0.f;
    #pragma unroll 8
    for (int cc = 0; cc < 32; ++cc)
        acc = fmaf(wrow[cc], sp[cc * 32], acc);
    u16 hi = f2bf(acc);
    u16 lo = f2bf(acc - bf2f(hi));
    const int s = hd >> 5, cslot = hd & 31;
    const int qt = cslot >> 3, e = cslot & 7;
    const int p = (o >> 1) & 3;
    size_t pos = ((size_t)(b * 2048 + s * 256 + o) << 5) + ((qt ^ p) << 3) + e;
    m2h[pos] = hi;
    m2l[pos] = lo;
}

// ---------------------------------------------------------------------------
// launch
// ---------------------------------------------------------------------------
extern "C" void kernel_launch(void* const* d_in, const int* in_sizes, int n_in,
                              void* d_out, int out_size, void* d_ws, size_t ws_size,
                              hipStream_t stream)
{
    const float* x      = (const float*)d_in[0];
    const float* w_qkv  = (const float*)d_in[1];
    const float* w_dw   = (const float*)d_in[2];
    const float* w_proj = (const float*)d_in[3];
    const float* temp   = (const float*)d_in[4];
    const float* a1     = (const float*)d_in[5];
    const float* a2     = (const float*)d_in[6];
    const float* a3     = (const float*)d_in[7];
    const float* a4     = (const float*)d_in[8];

    float* ws = (float*)d_ws;
    // region 0: qkv [B][768][HW] fp32 (25165824 f); dead after dwconv, then
    //           reused for sumsqp/part/attn/spar/m2h/m2l/vth/vtl.
    // region 1: dw  [B][768][HW] fp32 (25165824 f); its head holds xT/wh/wl
    //           during T1/T2/K1' (dead before dwconv writes region 1).
    float* qkv = ws;
    float* dwp = ws + (size_t)25165824;
    u16* xth = (u16*)dwp;                    // 2*8*16384*32 = 8388608 bf16
    u16* xtl = xth + (size_t)8388608;
    u16* whp = xtl + (size_t)8388608;        // 8*768*32 = 196608 bf16
    u16* wlp = whp + (size_t)196608;
    // region-0 small buffers (live after dwconv):
    float* sumsqp = ws;                      // 16*16*64 = 16384 floats
    float* part = ws + 16384;                // 262144 floats
    float* attn = ws + 16384 + 262144;       // 16384 floats
    float* spar = attn + 16384;              // 16384 floats
    u16* m2h = (u16*)(ws + 311296);          // 131072 u16 (65536 f)
    u16* m2l = (u16*)(ws + 311296 + 65536);  // 131072 u16
    u16* vth = (u16*)(ws + 524288);          // 8388608 u16 (4194304 f)
    u16* vtl = (u16*)(ws + 524288 + 4194304);

    // T1/T2: split W, transpose+split x (both pre-swizzled for LDS banks)
    wsplit<<<24, 256, 0, stream>>>(w_qkv, whp, wlp);
    transp_split<<<dim3(1024, 2), 256, 0, stream>>>(x, (long)DIMC * HW, xth, xtl);
    // K1': qkv = W_qkv @ x via split-bf16 MFMA
    gemm_mfma_split<<<dim3(6, 128, 2), 256, 0, stream>>>(
        whp, wlp, xth, xtl, qkv, 0, 768, (long)NCH * HW);
    // K2: depthwise 3x3
    dwconv3<<<dim3(16, NB * NCH), 256, 0, stream>>>(qkv, w_dw, dwp);
    // T3: transpose+split v (dw channels 512..767)
    transp_split<<<dim3(1024, 2), 256, 0, stream>>>(
        dwp + (size_t)512 * HW, (long)NCH * HW, vth, vtl);
    // K4: Gram partials + fused sumsq, then finish (inv-norms inline)
    gram_partial<<<dim3(16, 16), 256, 0, stream>>>(dwp, part, sumsqp);
    gram_finish<<<64, 256, 0, stream>>>(part, sumsqp, temp, attn);
    // K5: 4-way sparse softmax combine
    sparse_softmax<<<16, 1024, 0, stream>>>(attn, spar, a1, a2, a3, a4);
    // K6: fold proj @ spar into split-bf16 M2 (MFMA A-layout)
    build_m2_split<<<512, 256, 0, stream>>>(w_proj, spar, m2h, m2l);
    // K7': out = M2 @ v via split-bf16 MFMA (fp32 store to d_out)
    gemm_mfma_split<<<dim3(2, 128, 2), 256, 0, stream>>>(
        m2h, m2l, vth, vtl, (float*)d_out, 2048, 256, (long)DIMC * HW);
}

// Round 6
// 212.737 us; speedup vs baseline: 1.7970x; 1.1037x over previous
//
#include <hip/hip_runtime.h>
#include <stdint.h>

// Problem geometry (fixed)
#define HW     16384      // 128*128
#define IMGW   128
#define NCH    768        // 3*DIM
#define DIMC   256
#define NB     2
#define CPH    32         // channels per head

typedef unsigned short u16;
typedef unsigned int   u32;
typedef __attribute__((ext_vector_type(8))) short bf16x8;
typedef __attribute__((ext_vector_type(4))) float f32x4;

__device__ __forceinline__ float bf2f(u16 u) { return __uint_as_float(((u32)u) << 16); }
__device__ __forceinline__ u16 f2bf(float f) {
    u32 u = __float_as_uint(f);
    u += 0x7fffu + ((u >> 16) & 1u);
    return (u16)(u >> 16);
}

#define GLOAD16(gp, lp) __builtin_amdgcn_global_load_lds( \
    (const __attribute__((address_space(1))) void*)(gp),  \
    (__attribute__((address_space(3))) void*)(lp), 16, 0, 0)

// ---------------------------------------------------------------------------
// T1: split W_qkv into hi/lo bf16, layout [s=8][768 m][32 c] with quad swizzle
//     slot u within 64B window holds true quad (u ^ ((m>>1)&3))
// ---------------------------------------------------------------------------
__global__ __launch_bounds__(256)
void wsplit(const float* __restrict__ w, u16* __restrict__ wh, u16* __restrict__ wl)
{
    const int idx = blockIdx.x * 256 + threadIdx.x;   // 0..6143
    const int m = idx >> 3, s = idx & 7;
    const int p = (m >> 1) & 3;
    #pragma unroll
    for (int u = 0; u < 4; ++u) {
        const int cb = s * 32 + ((u ^ p) << 3);
        u32 hq[4], lq[4];
        #pragma unroll
        for (int e2 = 0; e2 < 4; ++e2) {
            float f0 = w[m * 256 + cb + 2 * e2];
            float f1 = w[m * 256 + cb + 2 * e2 + 1];
            u16 h0 = f2bf(f0); u16 l0 = f2bf(f0 - bf2f(h0));
            u16 h1 = f2bf(f1); u16 l1 = f2bf(f1 - bf2f(h1));
            hq[e2] = (u32)h0 | ((u32)h1 << 16);
            lq[e2] = (u32)l0 | ((u32)l1 << 16);
        }
        size_t rowb = ((size_t)(s * 768 + m)) << 6;   // 64 B per row
        uint4 hv; hv.x = hq[0]; hv.y = hq[1]; hv.z = hq[2]; hv.w = hq[3];
        uint4 lv; lv.x = lq[0]; lv.y = lq[1]; lv.z = lq[2]; lv.w = lq[3];
        *(uint4*)((char*)wh + rowb + (u << 4)) = hv;
        *(uint4*)((char*)wl + rowb + (u << 4)) = lv;
    }
}

// ---------------------------------------------------------------------------
// T2/T3: transpose + split src[bz][256 c][HW n] -> hi/lo bf16
// dst layout [b*8+s][16384 n][32 c], quad-swizzled: slot u holds quad u^((n>>1)&3)
// grid: dim3(1024, 2): blockIdx.x = nt(0..255) | ct(0..3)<<8
// ---------------------------------------------------------------------------
__global__ __launch_bounds__(256)
void transp_split(const float* __restrict__ src, long srcBatch,
                  u16* __restrict__ dsth, u16* __restrict__ dstl)
{
    __shared__ float Xs[64][68];
    const int bz = blockIdx.y;
    const int nt = blockIdx.x & 255;
    const int ct = blockIdx.x >> 8;
    const int n0 = nt * 64, c0 = ct * 64;
    const int t = threadIdx.x;
    const float* xb = src + (size_t)bz * srcBatch;

    #pragma unroll
    for (int it = 0; it < 4; ++it) {
        int cl = (t >> 4) + it * 16;
        int nl4 = (t & 15) << 2;
        float4 v = *(const float4*)(xb + (size_t)(c0 + cl) * HW + n0 + nl4);
        Xs[cl][nl4]     = v.x; Xs[cl][nl4 + 1] = v.y;
        Xs[cl][nl4 + 2] = v.z; Xs[cl][nl4 + 3] = v.w;
    }
    __syncthreads();

    const int nl = t >> 2, u = t & 3;
    const int p = (nl >> 1) & 3;                      // n0 is mult of 64
    #pragma unroll
    for (int sl = 0; sl < 2; ++sl) {
        const int s = (c0 >> 5) + sl;
        const int cb = sl * 32 + ((u ^ p) << 3);
        u32 hq[4], lq[4];
        #pragma unroll
        for (int e2 = 0; e2 < 4; ++e2) {
            float f0 = Xs[cb + 2 * e2][nl];
            float f1 = Xs[cb + 2 * e2 + 1][nl];
            u16 h0 = f2bf(f0); u16 l0 = f2bf(f0 - bf2f(h0));
            u16 h1 = f2bf(f1); u16 l1 = f2bf(f1 - bf2f(h1));
            hq[e2] = (u32)h0 | ((u32)h1 << 16);
            lq[e2] = (u32)l0 | ((u32)l1 << 16);
        }
        size_t rowb = ((size_t)((bz * 8 + s)) * 16384 + n0 + nl) << 6;
        uint4 hv; hv.x = hq[0]; hv.y = hq[1]; hv.z = hq[2]; hv.w = hq[3];
        uint4 lv; lv.x = lq[0]; lv.y = lq[1]; lv.z = lq[2]; lv.w = lq[3];
        *(uint4*)((char*)dsth + rowb + (u << 4)) = hv;
        *(uint4*)((char*)dstl + rowb + (u << 4)) = lv;
    }
}

// ---------------------------------------------------------------------------
// K1'/K7': C[bz][m][n] = sum_c A[m][c] * B[bz][c][n] via split-bf16 MFMA.
// 2-phase double-buffered pipeline (catalog T3 minimum recipe, m248 V1):
//   stage(next buf) issued BEFORE ds_read+MFMA of current; __syncthreads at
//   end of iter drains vmcnt after compute covered the latency.
// Tile 128m x 128n, K=256 (8 slices of 32), 4 waves (2x2), wave tile 64x64.
// 3 products: Ah*Bh + Ah*Bl + Al*Bh  (fp32-equivalent precision)
// LDS 2 x 32 KB: Ah/Al/Bh/Bl each [128 rows][64 B], quad-swizzled (pre-baked).
// ---------------------------------------------------------------------------
__global__ __launch_bounds__(256, 2)
void gemm_mfma_split(const u16* __restrict__ Ahp, const u16* __restrict__ Alp,
                     const u16* __restrict__ Bhp, const u16* __restrict__ Blp,
                     float* __restrict__ Cp, int aBatch, int aSlice, long cBatch)
{
    __shared__ char smem[65536];   // buf0/buf1: each {Ah 0, Al 8K, Bh 16K, Bl 24K}

    const int t    = threadIdx.x;
    const int lane = t & 63;
    const int w    = t >> 6;
    const int bz   = blockIdx.z;
    const int m0   = blockIdx.x * 128;
    const int n0   = blockIdx.y * 128;
    const int lrow  = lane >> 2;       // 0..15
    const int lquad = lane & 3;
    const int mh = w >> 1, nh = w & 1;
    // frag-read offset within a 16-row group: row (lane&15), swizzled quad
    const int swz = ((lane & 15) << 6) + ((((lane >> 4) ^ ((lane >> 1) & 3))) << 4);

    f32x4 acc[4][4];
    #pragma unroll
    for (int i = 0; i < 4; ++i)
        #pragma unroll
        for (int j = 0; j < 4; ++j)
            acc[i][j] = (f32x4){0.f, 0.f, 0.f, 0.f};

    // stage slice s into buffer buf (8 x 1KB global_load_lds per wave)
    auto stage = [&](int buf, int s) {
        const size_t arow0 = (size_t)bz * aBatch + (size_t)s * aSlice + m0;
        const size_t brow0 = ((size_t)(bz * 8 + s)) * 16384 + n0;
        char* base = smem + buf * 32768;
        #pragma unroll
        for (int i = 0; i < 8; ++i) {
            const int tile = i >> 1;                 // 0 Ah,1 Al,2 Bh,3 Bl
            const int r16  = ((i & 1) << 2) | w;     // 0..7
            char* dst = base + tile * 8192 + r16 * 1024;
            const char* src;
            if (tile == 0)
                src = (const char*)Ahp + ((arow0 + r16 * 16 + lrow) << 6) + (lquad << 4);
            else if (tile == 1)
                src = (const char*)Alp + ((arow0 + r16 * 16 + lrow) << 6) + (lquad << 4);
            else if (tile == 2)
                src = (const char*)Bhp + ((brow0 + r16 * 16 + lrow) << 6) + (lquad << 4);
            else
                src = (const char*)Blp + ((brow0 + r16 * 16 + lrow) << 6) + (lquad << 4);
            GLOAD16(src, dst);
        }
    };

    stage(0, 0);
    __syncthreads();

    #pragma unroll
    for (int s = 0; s < 8; ++s) {
        char* base = smem + (s & 1) * 32768;
        if (s < 7) stage((s + 1) & 1, s + 1);   // prefetch next slice (other buf)

        // ---- fragment loads from current buffer (conflict-free b128) ----
        bf16x8 ah[4], al[4], bh[4], bl[4];
        #pragma unroll
        for (int f = 0; f < 4; ++f) {
            const int aoff = (mh * 64 + f * 16) * 64 + swz;
            ah[f] = *(const bf16x8*)(base + aoff);
            al[f] = *(const bf16x8*)(base + 8192 + aoff);
            const int boff = (nh * 64 + f * 16) * 64 + swz;
            bh[f] = *(const bf16x8*)(base + 16384 + boff);
            bl[f] = *(const bf16x8*)(base + 24576 + boff);
        }

        // ---- 48 MFMAs: 16 frags x 3 split products ----
        #pragma unroll
        for (int fm = 0; fm < 4; ++fm)
            #pragma unroll
            for (int fn = 0; fn < 4; ++fn) {
                acc[fm][fn] = __builtin_amdgcn_mfma_f32_16x16x32_bf16(ah[fm], bh[fn], acc[fm][fn], 0, 0, 0);
                acc[fm][fn] = __builtin_amdgcn_mfma_f32_16x16x32_bf16(ah[fm], bl[fn], acc[fm][fn], 0, 0, 0);
                acc[fm][fn] = __builtin_amdgcn_mfma_f32_16x16x32_bf16(al[fm], bh[fn], acc[fm][fn], 0, 0, 0);
            }

        if (s < 7) __syncthreads();   // drains prefetch vmcnt after compute
    }

    // ---- epilogue: C/D layout col=lane&15, row=(lane>>4)*4+reg (m89) ----
    float* Cb = Cp + (size_t)bz * cBatch;
    #pragma unroll
    for (int fm = 0; fm < 4; ++fm) {
        const int mrow0 = m0 + mh * 64 + fm * 16 + ((lane >> 4) << 2);
        #pragma unroll
        for (int fn = 0; fn < 4; ++fn) {
            const int ncol = n0 + nh * 64 + fn * 16 + (lane & 15);
            #pragma unroll
            for (int r = 0; r < 4; ++r)
                Cb[(size_t)(mrow0 + r) * HW + ncol] = acc[fm][fn][r];
        }
    }
}

// ---------------------------------------------------------------------------
// K2: depthwise 3x3 SAME. 16 px/thread (4 rows x 4 cols, vertical row reuse).
// block 256 thr = 8 row-groups x 32 col-quads; tile 32 rows x 128 cols.
// grid: dim3(4, B*768). Tap order (dy,dx asc) matches previous bit-exactly.
// ---------------------------------------------------------------------------
__global__ __launch_bounds__(256)
void dwconv3(const float* __restrict__ in, const float* __restrict__ wdw,
             float* __restrict__ out)
{
    const int p  = blockIdx.y;                 // plane = bi*768 + ch
    const int t  = threadIdx.x;
    const int r0 = blockIdx.x * 32 + (t >> 5) * 4;
    const int c0 = (t & 31) << 2;

    const float* plane = in + (size_t)p * HW;
    const float* wp = wdw + (p % NCH) * 9;
    float w[9];
    #pragma unroll
    for (int i = 0; i < 9; ++i) w[i] = wp[i];

    // preload 6 input rows (r0-1 .. r0+4), 6 cols each (c0-1 .. c0+4)
    float rv[6][6];
    #pragma unroll
    for (int j = 0; j < 6; ++j) {
        const int ry = r0 - 1 + j;
        if (ry < 0 || ry >= IMGW) {
            #pragma unroll
            for (int k = 0; k < 6; ++k) rv[j][k] = 0.f;
        } else {
            const float* rp = plane + ry * IMGW;
            float4 vm = *reinterpret_cast<const float4*>(rp + c0);
            rv[j][0] = (c0 > 0)   ? rp[c0 - 1] : 0.f;
            rv[j][1] = vm.x; rv[j][2] = vm.y; rv[j][3] = vm.z; rv[j][4] = vm.w;
            rv[j][5] = (c0 < 124) ? rp[c0 + 4] : 0.f;
        }
    }

    #pragma unroll
    for (int rr = 0; rr < 4; ++rr) {
        float acc[4] = {0.f, 0.f, 0.f, 0.f};
        #pragma unroll
        for (int dy = 0; dy < 3; ++dy) {
            #pragma unroll
            for (int dx = 0; dx < 3; ++dx) {
                float wv = w[dy * 3 + dx];
                #pragma unroll
                for (int q = 0; q < 4; ++q)
                    acc[q] = fmaf(rv[rr + dy][q + dx], wv, acc[q]);
            }
        }
        float4 o4 = {acc[0], acc[1], acc[2], acc[3]};
        *reinterpret_cast<float4*>(out + (size_t)p * HW + (r0 + rr) * IMGW + c0) = o4;
    }
}

// ---------------------------------------------------------------------------
// K4: Gram partials + per-channel sumsq partials (l2norm fused in).
// grid (16 n-chunks, 16 bh). part: [chunk][bh][32*32]; sumsqp: [chunk][bh][64]
// ---------------------------------------------------------------------------
__global__ __launch_bounds__(256)
void gram_partial(const float* __restrict__ dw, float* __restrict__ part,
                  float* __restrict__ sumsqp)
{
    __shared__ float Qs[32][132];
    __shared__ float Ks[32][132];
    const int chunk = blockIdx.x;
    const int bh    = blockIdx.y;
    const int bi = bh >> 3, h = bh & 7;
    const float* qbase = dw + ((size_t)bi * NCH + h * CPH) * HW;
    const float* kbase = dw + ((size_t)bi * NCH + 256 + h * CPH) * HW;
    const int t = threadIdx.x;
    const int c = t >> 3, d0 = (t & 7) << 2;
    const int ch64 = t >> 2;          // 0..63 (0..31 q, 32..63 k)
    const int qtr  = t & 3;

    float acc[4] = {0.f, 0.f, 0.f, 0.f};
    float sq = 0.f;
    for (int sub = 0; sub < 8; ++sub) {
        int nbase = chunk * 1024 + sub * 128;
        __syncthreads();
        #pragma unroll
        for (int r = 0; r < 4; ++r) {
            int idx = t + r * 256;
            int row = idx >> 5, col = (idx & 31) << 2;
            *reinterpret_cast<float4*>(&Qs[row][col]) =
                *reinterpret_cast<const float4*>(qbase + (size_t)row * HW + nbase + col);
            *reinterpret_cast<float4*>(&Ks[row][col]) =
                *reinterpret_cast<const float4*>(kbase + (size_t)row * HW + nbase + col);
        }
        __syncthreads();
        #pragma unroll 8
        for (int n4 = 0; n4 < 32; ++n4) {
            float4 q4 = *reinterpret_cast<const float4*>(&Qs[c][n4 << 2]);
            #pragma unroll
            for (int j = 0; j < 4; ++j) {
                float4 k4 = *reinterpret_cast<const float4*>(&Ks[d0 + j][n4 << 2]);
                acc[j] = fmaf(q4.x, k4.x, acc[j]);
                acc[j] = fmaf(q4.y, k4.y, acc[j]);
                acc[j] = fmaf(q4.z, k4.z, acc[j]);
                acc[j] = fmaf(q4.w, k4.w, acc[j]);
            }
        }
        // fused sumsq: thread covers (ch64, quarter), stride-4 stagger keeps
        // the 4 quarter-lanes on distinct banks (132%32=4 -> bank 4c+qtr+4i)
        {
            const float* srow = (ch64 < 32) ? &Qs[ch64][0] : &Ks[ch64 - 32][0];
            #pragma unroll 8
            for (int i = 0; i < 32; ++i) {
                float v = srow[qtr + 4 * i];
                sq = fmaf(v, v, sq);
            }
        }
    }
    // reduce quarters (adjacent lanes within wave)
    sq += __shfl_xor(sq, 1);
    sq += __shfl_xor(sq, 2);
    if (qtr == 0) sumsqp[((size_t)chunk * 16 + bh) * 64 + ch64] = sq;

    float4 o4 = {acc[0], acc[1], acc[2], acc[3]};
    *reinterpret_cast<float4*>(part + ((size_t)chunk * 16 + bh) * 1024 + c * 32 + d0) = o4;
}

// ---------------------------------------------------------------------------
// K4b: reduce partials + apply inv norms (from sumsq partials) and temperature
// ---------------------------------------------------------------------------
__global__ __launch_bounds__(256)
void gram_finish(const float* __restrict__ part, const float* __restrict__ sumsqp,
                 const float* __restrict__ temp, float* __restrict__ attn)
{
    const int idx = blockIdx.x * 256 + threadIdx.x;  // 0..16383
    const int bh = idx >> 10;
    const int h = bh & 7;
    const int c = (idx >> 5) & 31, d = idx & 31;
    float s = 0.f, sqq = 0.f, sqk = 0.f;
    #pragma unroll
    for (int ch = 0; ch < 16; ++ch) {
        s   += part[(size_t)ch * 16384 + idx];
        sqq += sumsqp[((size_t)ch * 16 + bh) * 64 + c];
        sqk += sumsqp[((size_t)ch * 16 + bh) * 64 + 32 + d];
    }
    float iq = 1.f / fmaxf(sqrtf(sqq), 1e-12f);
    float ik = 1.f / fmaxf(sqrtf(sqk), 1e-12f);
    attn[idx] = s * iq * ik * temp[h];
}

// ---------------------------------------------------------------------------
// K5: rank-based 4-way sparse softmax combine. One block (1024 thr) per bh.
// ---------------------------------------------------------------------------
__global__ __launch_bounds__(1024)
void sparse_softmax(const float* __restrict__ attn, float* __restrict__ spar,
                    const float* __restrict__ a1, const float* __restrict__ a2,
                    const float* __restrict__ a3, const float* __restrict__ a4)
{
    __shared__ float xs[1024];
    __shared__ float red[16 * 4];
    __shared__ float vthr[4];
    __shared__ float msh;
    __shared__ float ssh[4];

    const int bh = blockIdx.x, t = threadIdx.x;
    float x = attn[bh * 1024 + t];
    xs[t] = x;
    __syncthreads();

    int g = 0, e = 0;
    for (int j = 0; j < 1024; ++j) {
        float v = xs[j];
        g += (v > x);
        e += (v == x);
    }
    if (g == 0) msh = x;  // all writers hold the identical max value
    const int topks[4] = {512, 682, 768, 819};
    #pragma unroll
    for (int kk = 0; kk < 4; ++kk)
        if (g <= topks[kk] - 1 && topks[kk] - 1 < g + e) vthr[kk] = x;  // rank-(topk-1) value
    __syncthreads();

    float m  = msh;
    float ex = expf(x - m);
    float v4[4];
    #pragma unroll
    for (int kk = 0; kk < 4; ++kk) v4[kk] = (x >= vthr[kk]) ? ex : 0.f;
    #pragma unroll
    for (int off = 32; off; off >>= 1)
        #pragma unroll
        for (int kk = 0; kk < 4; ++kk) v4[kk] += __shfl_down(v4[kk], off);
    const int lane = t & 63, wid = t >> 6;
    if (lane == 0) {
        #pragma unroll
        for (int kk = 0; kk < 4; ++kk) red[wid * 4 + kk] = v4[kk];
    }
    __syncthreads();
    if (t == 0) {
        float s0 = 0, s1 = 0, s2 = 0, s3 = 0;
        for (int w = 0; w < 16; ++w) {
            s0 += red[w * 4 + 0]; s1 += red[w * 4 + 1];
            s2 += red[w * 4 + 2]; s3 += red[w * 4 + 3];
        }
        ssh[0] = s0; ssh[1] = s1; ssh[2] = s2; ssh[3] = s3;
    }
    __syncthreads();

    float av[4] = {*a1, *a2, *a3, *a4};
    float coef = 0.f;
    #pragma unroll
    for (int kk = 0; kk < 4; ++kk)
        if (x >= vthr[kk]) coef += av[kk] / ssh[kk];
    spar[bh * 1024 + t] = ex * coef;
}

// ---------------------------------------------------------------------------
// K6: M2[b][o][hd] = sum_cc Wproj[o][h*32+cc]*spar[b,h,cc,d]; emit split bf16
// in MFMA A-layout: row = b*2048 + s*256 + o (s=hd>>5), 32 c-slots quad-swizzled
// ---------------------------------------------------------------------------
__global__ __launch_bounds__(256)
void build_m2_split(const float* __restrict__ wproj, const float* __restrict__ spar,
                    u16* __restrict__ m2h, u16* __restrict__ m2l)
{
    const int idx = blockIdx.x * 256 + threadIdx.x;  // 0..131071
    const int b = idx >> 16, o = (idx >> 8) & 255, hd = idx & 255;
    const int h = hd >> 5, d = hd & 31;
    const float* wrow = wproj + o * 256 + h * CPH;
    const float* sp = spar + (size_t)(b * 8 + h) * 1024 + d;
    float acc = 0.f;
    #pragma unroll 8
    for (int cc = 0; cc < 32; ++cc)
        acc = fmaf(wrow[cc], sp[cc * 32], acc);
    u16 hi = f2bf(acc);
    u16 lo = f2bf(acc - bf2f(hi));
    const int s = hd >> 5, cslot = hd & 31;
    const int qt = cslot >> 3, e = cslot & 7;
    const int p = (o >> 1) & 3;
    size_t pos = ((size_t)(b * 2048 + s * 256 + o) << 5) + ((qt ^ p) << 3) + e;
    m2h[pos] = hi;
    m2l[pos] = lo;
}

// ---------------------------------------------------------------------------
// launch
// ---------------------------------------------------------------------------
extern "C" void kernel_launch(void* const* d_in, const int* in_sizes, int n_in,
                              void* d_out, int out_size, void* d_ws, size_t ws_size,
                              hipStream_t stream)
{
    const float* x      = (const float*)d_in[0];
    const float* w_qkv  = (const float*)d_in[1];
    const float* w_dw   = (const float*)d_in[2];
    const float* w_proj = (const float*)d_in[3];
    const float* temp   = (const float*)d_in[4];
    const float* a1     = (const float*)d_in[5];
    const float* a2     = (const float*)d_in[6];
    const float* a3     = (const float*)d_in[7];
    const float* a4     = (const float*)d_in[8];

    float* ws = (float*)d_ws;
    // region 0: qkv [B][768][HW] fp32 (25165824 f); dead after dwconv, then
    //           reused for sumsqp/part/attn/spar/m2h/m2l/vth/vtl.
    // region 1: dw  [B][768][HW] fp32 (25165824 f); its head holds xT/wh/wl
    //           during T1/T2/K1' (dead before dwconv writes region 1).
    float* qkv = ws;
    float* dwp = ws + (size_t)25165824;
    u16* xth = (u16*)dwp;                    // 2*8*16384*32 = 8388608 bf16
    u16* xtl = xth + (size_t)8388608;
    u16* whp = xtl + (size_t)8388608;        // 8*768*32 = 196608 bf16
    u16* wlp = whp + (size_t)196608;
    // region-0 small buffers (live after dwconv):
    float* sumsqp = ws;                      // 16*16*64 = 16384 floats
    float* part = ws + 16384;                // 262144 floats
    float* attn = ws + 16384 + 262144;       // 16384 floats
    float* spar = attn + 16384;              // 16384 floats
    u16* m2h = (u16*)(ws + 311296);          // 131072 u16 (65536 f)
    u16* m2l = (u16*)(ws + 311296 + 65536);  // 131072 u16
    u16* vth = (u16*)(ws + 524288);          // 8388608 u16 (4194304 f)
    u16* vtl = (u16*)(ws + 524288 + 4194304);

    // T1/T2: split W, transpose+split x (both pre-swizzled for LDS banks)
    wsplit<<<24, 256, 0, stream>>>(w_qkv, whp, wlp);
    transp_split<<<dim3(1024, 2), 256, 0, stream>>>(x, (long)DIMC * HW, xth, xtl);
    // K1': qkv = W_qkv @ x via split-bf16 MFMA (2-phase pipelined)
    gemm_mfma_split<<<dim3(6, 128, 2), 256, 0, stream>>>(
        whp, wlp, xth, xtl, qkv, 0, 768, (long)NCH * HW);
    // K2: depthwise 3x3
    dwconv3<<<dim3(4, NB * NCH), 256, 0, stream>>>(qkv, w_dw, dwp);
    // T3: transpose+split v (dw channels 512..767)
    transp_split<<<dim3(1024, 2), 256, 0, stream>>>(
        dwp + (size_t)512 * HW, (long)NCH * HW, vth, vtl);
    // K4: Gram partials + fused sumsq, then finish (inv-norms inline)
    gram_partial<<<dim3(16, 16), 256, 0, stream>>>(dwp, part, sumsqp);
    gram_finish<<<64, 256, 0, stream>>>(part, sumsqp, temp, attn);
    // K5: 4-way sparse softmax combine
    sparse_softmax<<<16, 1024, 0, stream>>>(attn, spar, a1, a2, a3, a4);
    // K6: fold proj @ spar into split-bf16 M2 (MFMA A-layout)
    build_m2_split<<<512, 256, 0, stream>>>(w_proj, spar, m2h, m2l);
    // K7': out = M2 @ v via split-bf16 MFMA (fp32 store to d_out)
    gemm_mfma_split<<<dim3(2, 128, 2), 256, 0, stream>>>(
        m2h, m2l, vth, vtl, (float*)d_out, 2048, 256, (long)DIMC * HW);
}

// Round 7
// 177.526 us; speedup vs baseline: 2.1534x; 1.1983x over previous
//
#include <hip/hip_runtime.h>
#include <stdint.h>

// Problem geometry (fixed)
#define HW     16384      // 128*128
#define IMGW   128
#define NCH    768        // 3*DIM
#define DIMC   256
#define NB     2
#define CPH    32         // channels per head

typedef unsigned short u16;
typedef unsigned int   u32;
typedef __attribute__((ext_vector_type(8))) short bf16x8;
typedef __attribute__((ext_vector_type(4))) float f32x4;

__device__ __forceinline__ float bf2f(u16 u) { return __uint_as_float(((u32)u) << 16); }
__device__ __forceinline__ u16 f2bf(float f) {
    u32 u = __float_as_uint(f);
    u += 0x7fffu + ((u >> 16) & 1u);
    return (u16)(u >> 16);
}

#define GLOAD16(gp, lp) __builtin_amdgcn_global_load_lds( \
    (const __attribute__((address_space(1))) void*)(gp),  \
    (__attribute__((address_space(3))) void*)(lp), 16, 0, 0)

// ---------------------------------------------------------------------------
// T1: split W_qkv into hi/lo bf16, layout [s=8][768 m][32 c] with quad swizzle
//     slot u within 64B window holds true quad (u ^ ((m>>1)&3))
// ---------------------------------------------------------------------------
__global__ __launch_bounds__(256)
void wsplit(const float* __restrict__ w, u16* __restrict__ wh, u16* __restrict__ wl)
{
    const int idx = blockIdx.x * 256 + threadIdx.x;   // 0..6143
    const int m = idx >> 3, s = idx & 7;
    const int p = (m >> 1) & 3;
    #pragma unroll
    for (int u = 0; u < 4; ++u) {
        const int cb = s * 32 + ((u ^ p) << 3);
        u32 hq[4], lq[4];
        #pragma unroll
        for (int e2 = 0; e2 < 4; ++e2) {
            float f0 = w[m * 256 + cb + 2 * e2];
            float f1 = w[m * 256 + cb + 2 * e2 + 1];
            u16 h0 = f2bf(f0); u16 l0 = f2bf(f0 - bf2f(h0));
            u16 h1 = f2bf(f1); u16 l1 = f2bf(f1 - bf2f(h1));
            hq[e2] = (u32)h0 | ((u32)h1 << 16);
            lq[e2] = (u32)l0 | ((u32)l1 << 16);
        }
        size_t rowb = ((size_t)(s * 768 + m)) << 6;   // 64 B per row
        uint4 hv; hv.x = hq[0]; hv.y = hq[1]; hv.z = hq[2]; hv.w = hq[3];
        uint4 lv; lv.x = lq[0]; lv.y = lq[1]; lv.z = lq[2]; lv.w = lq[3];
        *(uint4*)((char*)wh + rowb + (u << 4)) = hv;
        *(uint4*)((char*)wl + rowb + (u << 4)) = lv;
    }
}

// ---------------------------------------------------------------------------
// T2: transpose + split x (fp32) -> xT hi/lo bf16
// dst layout [b*8+s][16384 n][32 c], quad-swizzled: slot u holds quad u^((n>>1)&3)
// grid: dim3(1024, 2): blockIdx.x = nt(0..255) | ct(0..3)<<8
// ---------------------------------------------------------------------------
__global__ __launch_bounds__(256)
void transp_split(const float* __restrict__ src, long srcBatch,
                  u16* __restrict__ dsth, u16* __restrict__ dstl)
{
    __shared__ float Xs[64][68];
    const int bz = blockIdx.y;
    const int nt = blockIdx.x & 255;
    const int ct = blockIdx.x >> 8;
    const int n0 = nt * 64, c0 = ct * 64;
    const int t = threadIdx.x;
    const float* xb = src + (size_t)bz * srcBatch;

    #pragma unroll
    for (int it = 0; it < 4; ++it) {
        int cl = (t >> 4) + it * 16;
        int nl4 = (t & 15) << 2;
        float4 v = *(const float4*)(xb + (size_t)(c0 + cl) * HW + n0 + nl4);
        Xs[cl][nl4]     = v.x; Xs[cl][nl4 + 1] = v.y;
        Xs[cl][nl4 + 2] = v.z; Xs[cl][nl4 + 3] = v.w;
    }
    __syncthreads();

    const int nl = t >> 2, u = t & 3;
    const int p = (nl >> 1) & 3;                      // n0 is mult of 64
    #pragma unroll
    for (int sl = 0; sl < 2; ++sl) {
        const int s = (c0 >> 5) + sl;
        const int cb = sl * 32 + ((u ^ p) << 3);
        u32 hq[4], lq[4];
        #pragma unroll
        for (int e2 = 0; e2 < 4; ++e2) {
            float f0 = Xs[cb + 2 * e2][nl];
            float f1 = Xs[cb + 2 * e2 + 1][nl];
            u16 h0 = f2bf(f0); u16 l0 = f2bf(f0 - bf2f(h0));
            u16 h1 = f2bf(f1); u16 l1 = f2bf(f1 - bf2f(h1));
            hq[e2] = (u32)h0 | ((u32)h1 << 16);
            lq[e2] = (u32)l0 | ((u32)l1 << 16);
        }
        size_t rowb = ((size_t)((bz * 8 + s)) * 16384 + n0 + nl) << 6;
        uint4 hv; hv.x = hq[0]; hv.y = hq[1]; hv.z = hq[2]; hv.w = hq[3];
        uint4 lv; lv.x = lq[0]; lv.y = lq[1]; lv.z = lq[2]; lv.w = lq[3];
        *(uint4*)((char*)dsth + rowb + (u << 4)) = hv;
        *(uint4*)((char*)dstl + rowb + (u << 4)) = lv;
    }
}

// ---------------------------------------------------------------------------
// T3: transpose v (bf16 in, hi-only out), same dst layout/swizzle as T2.
// ---------------------------------------------------------------------------
__global__ __launch_bounds__(256)
void transp_bf(const u16* __restrict__ src, long srcBatch, u16* __restrict__ dsth)
{
    __shared__ u16 Xs[64][66];   // pad 2 u16: bank = (row + (nl>>1)) % 32
    const int bz = blockIdx.y;
    const int nt = blockIdx.x & 255;
    const int ct = blockIdx.x >> 8;
    const int n0 = nt * 64, c0 = ct * 64;
    const int t = threadIdx.x;
    const u16* xb = src + (size_t)bz * srcBatch;

    #pragma unroll
    for (int it = 0; it < 4; ++it) {
        int cl = (t >> 4) + it * 16;
        int nl4 = (t & 15) << 2;
        ushort4 v = *(const ushort4*)(xb + (size_t)(c0 + cl) * HW + n0 + nl4);
        Xs[cl][nl4] = v.x; Xs[cl][nl4 + 1] = v.y;
        Xs[cl][nl4 + 2] = v.z; Xs[cl][nl4 + 3] = v.w;
    }
    __syncthreads();

    const int nl = t >> 2, u = t & 3;
    const int p = (nl >> 1) & 3;
    #pragma unroll
    for (int sl = 0; sl < 2; ++sl) {
        const int s = (c0 >> 5) + sl;
        const int cb = sl * 32 + ((u ^ p) << 3);
        u32 q[4];
        #pragma unroll
        for (int e2 = 0; e2 < 4; ++e2)
            q[e2] = (u32)Xs[cb + 2 * e2][nl] | ((u32)Xs[cb + 2 * e2 + 1][nl] << 16);
        size_t rowb = ((size_t)((bz * 8 + s)) * 16384 + n0 + nl) << 6;
        uint4 hv; hv.x = q[0]; hv.y = q[1]; hv.z = q[2]; hv.w = q[3];
        *(uint4*)((char*)dsth + rowb + (u << 4)) = hv;
    }
}

// ---------------------------------------------------------------------------
// K1'/K7': C[bz][m][n] = sum_c A[m][c] * B[bz][c][n] via split-bf16 MFMA.
// 2-phase double-buffered pipeline; XCD-chunked block swizzle (T1 catalog):
//   each XCD gets a contiguous slab of n-panels so the MBLKS m-blocks
//   re-reading a B-panel hit XCD-local L2.
// FULLB: B has hi+lo (3 products). !FULLB: B hi only (2 products: AhBh+AlBh).
// OUTBF16: store C as bf16 (else fp32).
// ---------------------------------------------------------------------------
template<bool FULLB, bool OUTBF16, int MBLKS>
__global__ __launch_bounds__(256, 2)
void gemm_mfma_split(const u16* __restrict__ Ahp, const u16* __restrict__ Alp,
                     const u16* __restrict__ Bhp, const u16* __restrict__ Blp,
                     void* __restrict__ Cp, int aBatch, int aSlice, long cBatch)
{
    constexpr int BUFSZ = FULLB ? 32768 : 24576;  // {Ah,Al,Bh[,Bl]} x 8KB
    __shared__ char smem[2 * BUFSZ];

    const int t    = threadIdx.x;
    const int lane = t & 63;
    const int w    = t >> 6;
    // XCD-chunked swizzle (nwg % 8 == 0)
    const int per = gridDim.x >> 3;
    const int wid = (blockIdx.x & 7) * per + (blockIdx.x >> 3);
    const int nglob = wid / MBLKS;               // m iterates fastest
    const int m0 = (wid % MBLKS) * 128;
    const int bz = nglob >> 7;
    const int n0 = (nglob & 127) * 128;

    const int lrow  = lane >> 2;       // 0..15
    const int lquad = lane & 3;
    const int mh = w >> 1, nh = w & 1;
    const int swz = ((lane & 15) << 6) + ((((lane >> 4) ^ ((lane >> 1) & 3))) << 4);

    f32x4 acc[4][4];
    #pragma unroll
    for (int i = 0; i < 4; ++i)
        #pragma unroll
        for (int j = 0; j < 4; ++j)
            acc[i][j] = (f32x4){0.f, 0.f, 0.f, 0.f};

    auto stage = [&](int buf, int s) {
        const size_t arow0 = (size_t)bz * aBatch + (size_t)s * aSlice + m0;
        const size_t brow0 = ((size_t)(bz * 8 + s)) * 16384 + n0;
        char* base = smem + buf * BUFSZ;
        constexpr int NCHK = FULLB ? 8 : 6;
        #pragma unroll
        for (int i = 0; i < NCHK; ++i) {
            const int tile = i >> 1;                 // 0 Ah,1 Al,2 Bh,3 Bl
            const int r16  = ((i & 1) << 2) | w;     // 0..7
            char* dst = base + tile * 8192 + r16 * 1024;
            const char* src;
            if (tile == 0)
                src = (const char*)Ahp + ((arow0 + r16 * 16 + lrow) << 6) + (lquad << 4);
            else if (tile == 1)
                src = (const char*)Alp + ((arow0 + r16 * 16 + lrow) << 6) + (lquad << 4);
            else if (tile == 2)
                src = (const char*)Bhp + ((brow0 + r16 * 16 + lrow) << 6) + (lquad << 4);
            else
                src = (const char*)Blp + ((brow0 + r16 * 16 + lrow) << 6) + (lquad << 4);
            GLOAD16(src, dst);
        }
    };

    stage(0, 0);
    __syncthreads();

    #pragma unroll
    for (int s = 0; s < 8; ++s) {
        char* base = smem + (s & 1) * BUFSZ;
        if (s < 7) stage((s + 1) & 1, s + 1);   // prefetch next slice (other buf)

        bf16x8 ah[4], al[4], bh[4], bl[4];
        #pragma unroll
        for (int f = 0; f < 4; ++f) {
            const int aoff = (mh * 64 + f * 16) * 64 + swz;
            ah[f] = *(const bf16x8*)(base + aoff);
            al[f] = *(const bf16x8*)(base + 8192 + aoff);
            const int boff = (nh * 64 + f * 16) * 64 + swz;
            bh[f] = *(const bf16x8*)(base + 16384 + boff);
            if (FULLB) bl[f] = *(const bf16x8*)(base + 24576 + boff);
        }

        #pragma unroll
        for (int fm = 0; fm < 4; ++fm)
            #pragma unroll
            for (int fn = 0; fn < 4; ++fn) {
                acc[fm][fn] = __builtin_amdgcn_mfma_f32_16x16x32_bf16(ah[fm], bh[fn], acc[fm][fn], 0, 0, 0);
                if (FULLB)
                    acc[fm][fn] = __builtin_amdgcn_mfma_f32_16x16x32_bf16(ah[fm], bl[fn], acc[fm][fn], 0, 0, 0);
                acc[fm][fn] = __builtin_amdgcn_mfma_f32_16x16x32_bf16(al[fm], bh[fn], acc[fm][fn], 0, 0, 0);
            }

        if (s < 7) __syncthreads();
    }

    // epilogue: C/D layout col=lane&15, row=(lane>>4)*4+reg (m89)
    #pragma unroll
    for (int fm = 0; fm < 4; ++fm) {
        const int mrow0 = m0 + mh * 64 + fm * 16 + ((lane >> 4) << 2);
        #pragma unroll
        for (int fn = 0; fn < 4; ++fn) {
            const int ncol = n0 + nh * 64 + fn * 16 + (lane & 15);
            if (OUTBF16) {
                u16* Cb = (u16*)Cp + (size_t)bz * cBatch;
                #pragma unroll
                for (int r = 0; r < 4; ++r)
                    Cb[(size_t)(mrow0 + r) * HW + ncol] = f2bf(acc[fm][fn][r]);
            } else {
                float* Cb = (float*)Cp + (size_t)bz * cBatch;
                #pragma unroll
                for (int r = 0; r < 4; ++r)
                    Cb[(size_t)(mrow0 + r) * HW + ncol] = acc[fm][fn][r];
            }
        }
    }
}

// ---------------------------------------------------------------------------
// K2: depthwise 3x3 SAME, bf16 in/out. 16 px/thread (4 rows x 4 cols).
// block 256 = 8 row-groups x 32 col-quads; tile 32 x 128; grid (4, B*768)
// ---------------------------------------------------------------------------
__global__ __launch_bounds__(256)
void dwconv3(const u16* __restrict__ in, const float* __restrict__ wdw,
             u16* __restrict__ out)
{
    const int p  = blockIdx.y;                 // plane = bi*768 + ch
    const int t  = threadIdx.x;
    const int r0 = blockIdx.x * 32 + (t >> 5) * 4;
    const int c0 = (t & 31) << 2;

    const u16* plane = in + (size_t)p * HW;
    const float* wp = wdw + (p % NCH) * 9;
    float w[9];
    #pragma unroll
    for (int i = 0; i < 9; ++i) w[i] = wp[i];

    float rv[6][6];
    #pragma unroll
    for (int j = 0; j < 6; ++j) {
        const int ry = r0 - 1 + j;
        if (ry < 0 || ry >= IMGW) {
            #pragma unroll
            for (int k = 0; k < 6; ++k) rv[j][k] = 0.f;
        } else {
            const u16* rp = plane + ry * IMGW;
            ushort4 vm = *(const ushort4*)(rp + c0);
            rv[j][0] = (c0 > 0)   ? bf2f(rp[c0 - 1]) : 0.f;
            rv[j][1] = bf2f(vm.x); rv[j][2] = bf2f(vm.y);
            rv[j][3] = bf2f(vm.z); rv[j][4] = bf2f(vm.w);
            rv[j][5] = (c0 < 124) ? bf2f(rp[c0 + 4]) : 0.f;
        }
    }

    #pragma unroll
    for (int rr = 0; rr < 4; ++rr) {
        float acc[4] = {0.f, 0.f, 0.f, 0.f};
        #pragma unroll
        for (int dy = 0; dy < 3; ++dy) {
            #pragma unroll
            for (int dx = 0; dx < 3; ++dx) {
                float wv = w[dy * 3 + dx];
                #pragma unroll
                for (int q = 0; q < 4; ++q)
                    acc[q] = fmaf(rv[rr + dy][q + dx], wv, acc[q]);
            }
        }
        ushort4 o4;
        o4.x = f2bf(acc[0]); o4.y = f2bf(acc[1]);
        o4.z = f2bf(acc[2]); o4.w = f2bf(acc[3]);
        *(ushort4*)(out + (size_t)p * HW + (r0 + rr) * IMGW + c0) = o4;
    }
}

// ---------------------------------------------------------------------------
// K4: Gram partials + per-channel sumsq partials (l2norm fused), bf16 input.
// grid (16 n-chunks, 16 bh). part: [chunk][bh][32*32]; sumsqp: [chunk][bh][64]
// ---------------------------------------------------------------------------
__device__ __forceinline__ void unpack8(float* d, uint4 v) {
    u32 a[4] = {v.x, v.y, v.z, v.w};
    #pragma unroll
    for (int i = 0; i < 4; ++i) {
        d[2 * i]     = __uint_as_float(a[i] << 16);
        d[2 * i + 1] = __uint_as_float(a[i] & 0xffff0000u);
    }
}

__global__ __launch_bounds__(256)
void gram_partial(const u16* __restrict__ dw, float* __restrict__ part,
                  float* __restrict__ sumsqp)
{
    __shared__ float Qs[32][132];
    __shared__ float Ks[32][132];
    const int chunk = blockIdx.x;
    const int bh    = blockIdx.y;
    const int bi = bh >> 3, h = bh & 7;
    const u16* qbase = dw + ((size_t)bi * NCH + h * CPH) * HW;
    const u16* kbase = dw + ((size_t)bi * NCH + 256 + h * CPH) * HW;
    const int t = threadIdx.x;
    const int c = t >> 3, d0 = (t & 7) << 2;
    const int ch64 = t >> 2;          // 0..63 (0..31 q, 32..63 k)
    const int qtr  = t & 3;

    float acc[4] = {0.f, 0.f, 0.f, 0.f};
    float sq = 0.f;
    for (int sub = 0; sub < 8; ++sub) {
        int nbase = chunk * 1024 + sub * 128;
        __syncthreads();
        #pragma unroll
        for (int r = 0; r < 2; ++r) {
            int idx = t + r * 256;           // 0..511
            int row = idx >> 4;              // 0..31
            int col = (idx & 15) << 3;       // 0..120
            uint4 qv = *(const uint4*)(qbase + (size_t)row * HW + nbase + col);
            uint4 kv = *(const uint4*)(kbase + (size_t)row * HW + nbase + col);
            unpack8(&Qs[row][col], qv);
            unpack8(&Ks[row][col], kv);
        }
        __syncthreads();
        #pragma unroll 8
        for (int n4 = 0; n4 < 32; ++n4) {
            float4 q4 = *reinterpret_cast<const float4*>(&Qs[c][n4 << 2]);
            #pragma unroll
            for (int j = 0; j < 4; ++j) {
                float4 k4 = *reinterpret_cast<const float4*>(&Ks[d0 + j][n4 << 2]);
                acc[j] = fmaf(q4.x, k4.x, acc[j]);
                acc[j] = fmaf(q4.y, k4.y, acc[j]);
                acc[j] = fmaf(q4.z, k4.z, acc[j]);
                acc[j] = fmaf(q4.w, k4.w, acc[j]);
            }
        }
        {
            const float* srow = (ch64 < 32) ? &Qs[ch64][0] : &Ks[ch64 - 32][0];
            #pragma unroll 8
            for (int i = 0; i < 32; ++i) {
                float v = srow[qtr + 4 * i];
                sq = fmaf(v, v, sq);
            }
        }
    }
    sq += __shfl_xor(sq, 1);
    sq += __shfl_xor(sq, 2);
    if (qtr == 0) sumsqp[((size_t)chunk * 16 + bh) * 64 + ch64] = sq;

    float4 o4 = {acc[0], acc[1], acc[2], acc[3]};
    *reinterpret_cast<float4*>(part + ((size_t)chunk * 16 + bh) * 1024 + c * 32 + d0) = o4;
}

// ---------------------------------------------------------------------------
// K4b: reduce partials + apply inv norms (from sumsq partials) and temperature
// ---------------------------------------------------------------------------
__global__ __launch_bounds__(256)
void gram_finish(const float* __restrict__ part, const float* __restrict__ sumsqp,
                 const float* __restrict__ temp, float* __restrict__ attn)
{
    const int idx = blockIdx.x * 256 + threadIdx.x;  // 0..16383
    const int bh = idx >> 10;
    const int h = bh & 7;
    const int c = (idx >> 5) & 31, d = idx & 31;
    float s = 0.f, sqq = 0.f, sqk = 0.f;
    #pragma unroll
    for (int ch = 0; ch < 16; ++ch) {
        s   += part[(size_t)ch * 16384 + idx];
        sqq += sumsqp[((size_t)ch * 16 + bh) * 64 + c];
        sqk += sumsqp[((size_t)ch * 16 + bh) * 64 + 32 + d];
    }
    float iq = 1.f / fmaxf(sqrtf(sqq), 1e-12f);
    float ik = 1.f / fmaxf(sqrtf(sqk), 1e-12f);
    attn[idx] = s * iq * ik * temp[h];
}

// ---------------------------------------------------------------------------
// K5: rank-based 4-way sparse softmax combine. One block (1024 thr) per bh.
// ---------------------------------------------------------------------------
__global__ __launch_bounds__(1024)
void sparse_softmax(const float* __restrict__ attn, float* __restrict__ spar,
                    const float* __restrict__ a1, const float* __restrict__ a2,
                    const float* __restrict__ a3, const float* __restrict__ a4)
{
    __shared__ float xs[1024];
    __shared__ float red[16 * 4];
    __shared__ float vthr[4];
    __shared__ float msh;
    __shared__ float ssh[4];

    const int bh = blockIdx.x, t = threadIdx.x;
    float x = attn[bh * 1024 + t];
    xs[t] = x;
    __syncthreads();

    int g = 0, e = 0;
    for (int j = 0; j < 1024; ++j) {
        float v = xs[j];
        g += (v > x);
        e += (v == x);
    }
    if (g == 0) msh = x;  // all writers hold the identical max value
    const int topks[4] = {512, 682, 768, 819};
    #pragma unroll
    for (int kk = 0; kk < 4; ++kk)
        if (g <= topks[kk] - 1 && topks[kk] - 1 < g + e) vthr[kk] = x;  // rank-(topk-1) value
    __syncthreads();

    float m  = msh;
    float ex = expf(x - m);
    float v4[4];
    #pragma unroll
    for (int kk = 0; kk < 4; ++kk) v4[kk] = (x >= vthr[kk]) ? ex : 0.f;
    #pragma unroll
    for (int off = 32; off; off >>= 1)
        #pragma unroll
        for (int kk = 0; kk < 4; ++kk) v4[kk] += __shfl_down(v4[kk], off);
    const int lane = t & 63, wid = t >> 6;
    if (lane == 0) {
        #pragma unroll
        for (int kk = 0; kk < 4; ++kk) red[wid * 4 + kk] = v4[kk];
    }
    __syncthreads();
    if (t == 0) {
        float s0 = 0, s1 = 0, s2 = 0, s3 = 0;
        for (int w = 0; w < 16; ++w) {
            s0 += red[w * 4 + 0]; s1 += red[w * 4 + 1];
            s2 += red[w * 4 + 2]; s3 += red[w * 4 + 3];
        }
        ssh[0] = s0; ssh[1] = s1; ssh[2] = s2; ssh[3] = s3;
    }
    __syncthreads();

    float av[4] = {*a1, *a2, *a3, *a4};
    float coef = 0.f;
    #pragma unroll
    for (int kk = 0; kk < 4; ++kk)
        if (x >= vthr[kk]) coef += av[kk] / ssh[kk];
    spar[bh * 1024 + t] = ex * coef;
}

// ---------------------------------------------------------------------------
// K6: M2[b][o][hd] = sum_cc Wproj[o][h*32+cc]*spar[b,h,cc,d]; emit split bf16
// in MFMA A-layout: row = b*2048 + s*256 + o (s=hd>>5), 32 c-slots quad-swizzled
// ---------------------------------------------------------------------------
__global__ __launch_bounds__(256)
void build_m2_split(const float* __restrict__ wproj, const float* __restrict__ spar,
                    u16* __restrict__ m2h, u16* __restrict__ m2l)
{
    const int idx = blockIdx.x * 256 + threadIdx.x;  // 0..131071
    const int b = idx >> 16, o = (idx >> 8) & 255, hd = idx & 255;
    const int h = hd >> 5, d = hd & 31;
    const float* wrow = wproj + o * 256 + h * CPH;
    const float* sp = spar + (size_t)(b * 8 + h) * 1024 + d;
    float acc = 0.f;
    #pragma unroll 8
    for (int cc = 0; cc < 32; ++cc)
        acc = fmaf(wrow[cc], sp[cc * 32], acc);
    u16 hi = f2bf(acc);
    u16 lo = f2bf(acc - bf2f(hi));
    const int s = hd >> 5, cslot = hd & 31;
    const int qt = cslot >> 3, e = cslot & 7;
    const int p = (o >> 1) & 3;
    size_t pos = ((size_t)(b * 2048 + s * 256 + o) << 5) + ((qt ^ p) << 3) + e;
    m2h[pos] = hi;
    m2l[pos] = lo;
}

// ---------------------------------------------------------------------------
// launch
// ---------------------------------------------------------------------------
extern "C" void kernel_launch(void* const* d_in, const int* in_sizes, int n_in,
                              void* d_out, int out_size, void* d_ws, size_t ws_size,
                              hipStream_t stream)
{
    const float* x      = (const float*)d_in[0];
    const float* w_qkv  = (const float*)d_in[1];
    const float* w_dw   = (const float*)d_in[2];
    const float* w_proj = (const float*)d_in[3];
    const float* temp   = (const float*)d_in[4];
    const float* a1     = (const float*)d_in[5];
    const float* a2     = (const float*)d_in[6];
    const float* a3     = (const float*)d_in[7];
    const float* a4     = (const float*)d_in[8];

    float* ws = (float*)d_ws;
    // region 0 floats [0, 25165824):
    //   qkvb bf16 [2][768][HW] (12582912 f-worth), dead after dwconv;
    //   vth  bf16 at f-ofs 12582912 (4194304 f-worth), written post-dwconv;
    //   small buffers (sumsqp/part/attn/spar/m2) overlay [0, 442368) post-dwconv.
    // region 1 floats [25165824, ...): xth/xtl/wh/wl during K1', then dwb bf16.
    u16* qkvb = (u16*)ws;
    u16* vth  = (u16*)(ws + 12582912);
    float* sumsqp = ws;                      // 16384 floats
    float* part = ws + 16384;                // 262144 floats
    float* attn = ws + 16384 + 262144;       // 16384 floats
    float* spar = attn + 16384;              // 16384 floats
    u16* m2h = (u16*)(ws + 311296);          // 131072 u16
    u16* m2l = (u16*)(ws + 311296 + 65536);  // 131072 u16
    float* r1 = ws + (size_t)25165824;
    u16* xth = (u16*)r1;                     // 8388608 u16
    u16* xtl = xth + (size_t)8388608;
    u16* whp = xtl + (size_t)8388608;        // 196608 u16
    u16* wlp = whp + (size_t)196608;
    u16* dwb = (u16*)r1;                     // [2][768][HW] bf16 (after K1')

    // T1/T2: split W, transpose+split x (pre-swizzled for LDS banks)
    wsplit<<<24, 256, 0, stream>>>(w_qkv, whp, wlp);
    transp_split<<<dim3(1024, 2), 256, 0, stream>>>(x, (long)DIMC * HW, xth, xtl);
    // K1': qkv = W_qkv @ x (split-bf16 MFMA, 2-phase, XCD swizzle, bf16 out)
    gemm_mfma_split<true, true, 6><<<1536, 256, 0, stream>>>(
        whp, wlp, xth, xtl, qkvb, 0, 768, (long)NCH * HW);
    // K2: depthwise 3x3 (bf16 in/out)
    dwconv3<<<dim3(4, NB * NCH), 256, 0, stream>>>(qkvb, w_dw, dwb);
    // T3: transpose v (bf16, hi only)
    transp_bf<<<dim3(1024, 2), 256, 0, stream>>>(
        dwb + (size_t)512 * HW, (long)NCH * HW, vth);
    // K4: Gram partials + fused sumsq, then finish
    gram_partial<<<dim3(16, 16), 256, 0, stream>>>(dwb, part, sumsqp);
    gram_finish<<<64, 256, 0, stream>>>(part, sumsqp, temp, attn);
    // K5: 4-way sparse softmax combine
    sparse_softmax<<<16, 1024, 0, stream>>>(attn, spar, a1, a2, a3, a4);
    // K6: fold proj @ spar into split-bf16 M2 (MFMA A-layout)
    build_m2_split<<<512, 256, 0, stream>>>(w_proj, spar, m2h, m2l);
    // K7': out = M2 @ v (2-product split MFMA, fp32 out)
    gemm_mfma_split<false, false, 2><<<512, 256, 0, stream>>>(
        m2h, m2l, vth, nullptr, d_out, 2048, 256, (long)DIMC * HW);
}

// Round 8
// 148.278 us; speedup vs baseline: 2.5782x; 1.1973x over previous
//
#include <hip/hip_runtime.h>
#include <stdint.h>

// Problem geometry (fixed)
#define HW     16384      // 128*128
#define IMGW   128
#define NCH    768        // 3*DIM
#define DIMC   256
#define NB     2
#define CPH    32         // channels per head

typedef unsigned short u16;
typedef unsigned int   u32;
typedef __attribute__((ext_vector_type(8))) short bf16x8;
typedef __attribute__((ext_vector_type(4))) float f32x4;

__device__ __forceinline__ float bf2f(u16 u) { return __uint_as_float(((u32)u) << 16); }
__device__ __forceinline__ u16 f2bf(float f) {
    u32 u = __float_as_uint(f);
    u += 0x7fffu + ((u >> 16) & 1u);
    return (u16)(u >> 16);
}

#define GLOAD16(gp, lp) __builtin_amdgcn_global_load_lds( \
    (const __attribute__((address_space(1))) void*)(gp),  \
    (__attribute__((address_space(3))) void*)(lp), 16, 0, 0)

// ---------------------------------------------------------------------------
// T1: split W_qkv into hi/lo bf16, layout [s=8][768 m][32 c] with quad swizzle
//     slot u within 64B window holds true quad (u ^ ((m>>1)&3))
// ---------------------------------------------------------------------------
__global__ __launch_bounds__(256)
void wsplit(const float* __restrict__ w, u16* __restrict__ wh, u16* __restrict__ wl)
{
    const int idx = blockIdx.x * 256 + threadIdx.x;   // 0..6143
    const int m = idx >> 3, s = idx & 7;
    const int p = (m >> 1) & 3;
    #pragma unroll
    for (int u = 0; u < 4; ++u) {
        const int cb = s * 32 + ((u ^ p) << 3);
        u32 hq[4], lq[4];
        #pragma unroll
        for (int e2 = 0; e2 < 4; ++e2) {
            float f0 = w[m * 256 + cb + 2 * e2];
            float f1 = w[m * 256 + cb + 2 * e2 + 1];
            u16 h0 = f2bf(f0); u16 l0 = f2bf(f0 - bf2f(h0));
            u16 h1 = f2bf(f1); u16 l1 = f2bf(f1 - bf2f(h1));
            hq[e2] = (u32)h0 | ((u32)h1 << 16);
            lq[e2] = (u32)l0 | ((u32)l1 << 16);
        }
        size_t rowb = ((size_t)(s * 768 + m)) << 6;   // 64 B per row
        uint4 hv; hv.x = hq[0]; hv.y = hq[1]; hv.z = hq[2]; hv.w = hq[3];
        uint4 lv; lv.x = lq[0]; lv.y = lq[1]; lv.z = lq[2]; lv.w = lq[3];
        *(uint4*)((char*)wh + rowb + (u << 4)) = hv;
        *(uint4*)((char*)wl + rowb + (u << 4)) = lv;
    }
}

// ---------------------------------------------------------------------------
// T2: transpose + split x (fp32) -> xT hi/lo bf16
// dst layout [b*8+s][16384 n][32 c], quad-swizzled: slot u holds quad u^((n>>1)&3)
// grid: dim3(1024, 2): blockIdx.x = nt(0..255) | ct(0..3)<<8
// ---------------------------------------------------------------------------
__global__ __launch_bounds__(256)
void transp_split(const float* __restrict__ src, long srcBatch,
                  u16* __restrict__ dsth, u16* __restrict__ dstl)
{
    __shared__ float Xs[64][68];
    const int bz = blockIdx.y;
    const int nt = blockIdx.x & 255;
    const int ct = blockIdx.x >> 8;
    const int n0 = nt * 64, c0 = ct * 64;
    const int t = threadIdx.x;
    const float* xb = src + (size_t)bz * srcBatch;

    #pragma unroll
    for (int it = 0; it < 4; ++it) {
        int cl = (t >> 4) + it * 16;
        int nl4 = (t & 15) << 2;
        float4 v = *(const float4*)(xb + (size_t)(c0 + cl) * HW + n0 + nl4);
        Xs[cl][nl4]     = v.x; Xs[cl][nl4 + 1] = v.y;
        Xs[cl][nl4 + 2] = v.z; Xs[cl][nl4 + 3] = v.w;
    }
    __syncthreads();

    const int nl = t >> 2, u = t & 3;
    const int p = (nl >> 1) & 3;                      // n0 is mult of 64
    #pragma unroll
    for (int sl = 0; sl < 2; ++sl) {
        const int s = (c0 >> 5) + sl;
        const int cb = sl * 32 + ((u ^ p) << 3);
        u32 hq[4], lq[4];
        #pragma unroll
        for (int e2 = 0; e2 < 4; ++e2) {
            float f0 = Xs[cb + 2 * e2][nl];
            float f1 = Xs[cb + 2 * e2 + 1][nl];
            u16 h0 = f2bf(f0); u16 l0 = f2bf(f0 - bf2f(h0));
            u16 h1 = f2bf(f1); u16 l1 = f2bf(f1 - bf2f(h1));
            hq[e2] = (u32)h0 | ((u32)h1 << 16);
            lq[e2] = (u32)l0 | ((u32)l1 << 16);
        }
        size_t rowb = ((size_t)((bz * 8 + s)) * 16384 + n0 + nl) << 6;
        uint4 hv; hv.x = hq[0]; hv.y = hq[1]; hv.z = hq[2]; hv.w = hq[3];
        uint4 lv; lv.x = lq[0]; lv.y = lq[1]; lv.z = lq[2]; lv.w = lq[3];
        *(uint4*)((char*)dsth + rowb + (u << 4)) = hv;
        *(uint4*)((char*)dstl + rowb + (u << 4)) = lv;
    }
}

// ---------------------------------------------------------------------------
// T3: transpose v (bf16 in, hi-only out), same dst layout/swizzle as T2.
// ---------------------------------------------------------------------------
__global__ __launch_bounds__(256)
void transp_bf(const u16* __restrict__ src, long srcBatch, u16* __restrict__ dsth)
{
    __shared__ u16 Xs[64][66];
    const int bz = blockIdx.y;
    const int nt = blockIdx.x & 255;
    const int ct = blockIdx.x >> 8;
    const int n0 = nt * 64, c0 = ct * 64;
    const int t = threadIdx.x;
    const u16* xb = src + (size_t)bz * srcBatch;

    #pragma unroll
    for (int it = 0; it < 4; ++it) {
        int cl = (t >> 4) + it * 16;
        int nl4 = (t & 15) << 2;
        ushort4 v = *(const ushort4*)(xb + (size_t)(c0 + cl) * HW + n0 + nl4);
        Xs[cl][nl4] = v.x; Xs[cl][nl4 + 1] = v.y;
        Xs[cl][nl4 + 2] = v.z; Xs[cl][nl4 + 3] = v.w;
    }
    __syncthreads();

    const int nl = t >> 2, u = t & 3;
    const int p = (nl >> 1) & 3;
    #pragma unroll
    for (int sl = 0; sl < 2; ++sl) {
        const int s = (c0 >> 5) + sl;
        const int cb = sl * 32 + ((u ^ p) << 3);
        u32 q[4];
        #pragma unroll
        for (int e2 = 0; e2 < 4; ++e2)
            q[e2] = (u32)Xs[cb + 2 * e2][nl] | ((u32)Xs[cb + 2 * e2 + 1][nl] << 16);
        size_t rowb = ((size_t)((bz * 8 + s)) * 16384 + n0 + nl) << 6;
        uint4 hv; hv.x = q[0]; hv.y = q[1]; hv.z = q[2]; hv.w = q[3];
        *(uint4*)((char*)dsth + rowb + (u << 4)) = hv;
    }
}

// ---------------------------------------------------------------------------
// K1'/K7': C[bz][m][n] = sum_c A[m][c] * B[bz][c][n] via split-bf16 MFMA.
// 2-phase double-buffered pipeline; XCD-chunked block swizzle.
// FULLB: B has hi+lo (3 products). !FULLB: B hi only (2 products).
// OUTBF16: store C as bf16 (else fp32).
// ---------------------------------------------------------------------------
template<bool FULLB, bool OUTBF16, int MBLKS>
__global__ __launch_bounds__(256, 2)
void gemm_mfma_split(const u16* __restrict__ Ahp, const u16* __restrict__ Alp,
                     const u16* __restrict__ Bhp, const u16* __restrict__ Blp,
                     void* __restrict__ Cp, int aBatch, int aSlice, long cBatch)
{
    constexpr int BUFSZ = FULLB ? 32768 : 24576;  // {Ah,Al,Bh[,Bl]} x 8KB
    __shared__ char smem[2 * BUFSZ];

    const int t    = threadIdx.x;
    const int lane = t & 63;
    const int w    = t >> 6;
    // XCD-chunked swizzle (nwg % 8 == 0)
    const int per = gridDim.x >> 3;
    const int wid = (blockIdx.x & 7) * per + (blockIdx.x >> 3);
    const int nglob = wid / MBLKS;               // m iterates fastest
    const int m0 = (wid % MBLKS) * 128;
    const int bz = nglob >> 7;
    const int n0 = (nglob & 127) * 128;

    const int lrow  = lane >> 2;       // 0..15
    const int lquad = lane & 3;
    const int mh = w >> 1, nh = w & 1;
    const int swz = ((lane & 15) << 6) + ((((lane >> 4) ^ ((lane >> 1) & 3))) << 4);

    f32x4 acc[4][4];
    #pragma unroll
    for (int i = 0; i < 4; ++i)
        #pragma unroll
        for (int j = 0; j < 4; ++j)
            acc[i][j] = (f32x4){0.f, 0.f, 0.f, 0.f};

    auto stage = [&](int buf, int s) {
        const size_t arow0 = (size_t)bz * aBatch + (size_t)s * aSlice + m0;
        const size_t brow0 = ((size_t)(bz * 8 + s)) * 16384 + n0;
        char* base = smem + buf * BUFSZ;
        constexpr int NCHK = FULLB ? 8 : 6;
        #pragma unroll
        for (int i = 0; i < NCHK; ++i) {
            const int tile = i >> 1;                 // 0 Ah,1 Al,2 Bh,3 Bl
            const int r16  = ((i & 1) << 2) | w;     // 0..7
            char* dst = base + tile * 8192 + r16 * 1024;
            const char* src;
            if (tile == 0)
                src = (const char*)Ahp + ((arow0 + r16 * 16 + lrow) << 6) + (lquad << 4);
            else if (tile == 1)
                src = (const char*)Alp + ((arow0 + r16 * 16 + lrow) << 6) + (lquad << 4);
            else if (tile == 2)
                src = (const char*)Bhp + ((brow0 + r16 * 16 + lrow) << 6) + (lquad << 4);
            else
                src = (const char*)Blp + ((brow0 + r16 * 16 + lrow) << 6) + (lquad << 4);
            GLOAD16(src, dst);
        }
    };

    stage(0, 0);
    __syncthreads();

    #pragma unroll
    for (int s = 0; s < 8; ++s) {
        char* base = smem + (s & 1) * BUFSZ;
        if (s < 7) stage((s + 1) & 1, s + 1);   // prefetch next slice (other buf)

        bf16x8 ah[4], al[4], bh[4], bl[4];
        #pragma unroll
        for (int f = 0; f < 4; ++f) {
            const int aoff = (mh * 64 + f * 16) * 64 + swz;
            ah[f] = *(const bf16x8*)(base + aoff);
            al[f] = *(const bf16x8*)(base + 8192 + aoff);
            const int boff = (nh * 64 + f * 16) * 64 + swz;
            bh[f] = *(const bf16x8*)(base + 16384 + boff);
            if (FULLB) bl[f] = *(const bf16x8*)(base + 24576 + boff);
        }

        #pragma unroll
        for (int fm = 0; fm < 4; ++fm)
            #pragma unroll
            for (int fn = 0; fn < 4; ++fn) {
                acc[fm][fn] = __builtin_amdgcn_mfma_f32_16x16x32_bf16(ah[fm], bh[fn], acc[fm][fn], 0, 0, 0);
                if (FULLB)
                    acc[fm][fn] = __builtin_amdgcn_mfma_f32_16x16x32_bf16(ah[fm], bl[fn], acc[fm][fn], 0, 0, 0);
                acc[fm][fn] = __builtin_amdgcn_mfma_f32_16x16x32_bf16(al[fm], bh[fn], acc[fm][fn], 0, 0, 0);
            }

        if (s < 7) __syncthreads();
    }

    // epilogue: C/D layout col=lane&15, row=(lane>>4)*4+reg (m89)
    #pragma unroll
    for (int fm = 0; fm < 4; ++fm) {
        const int mrow0 = m0 + mh * 64 + fm * 16 + ((lane >> 4) << 2);
        #pragma unroll
        for (int fn = 0; fn < 4; ++fn) {
            const int ncol = n0 + nh * 64 + fn * 16 + (lane & 15);
            if (OUTBF16) {
                u16* Cb = (u16*)Cp + (size_t)bz * cBatch;
                #pragma unroll
                for (int r = 0; r < 4; ++r)
                    Cb[(size_t)(mrow0 + r) * HW + ncol] = f2bf(acc[fm][fn][r]);
            } else {
                float* Cb = (float*)Cp + (size_t)bz * cBatch;
                #pragma unroll
                for (int r = 0; r < 4; ++r)
                    Cb[(size_t)(mrow0 + r) * HW + ncol] = acc[fm][fn][r];
            }
        }
    }
}

// ---------------------------------------------------------------------------
// K2: depthwise 3x3 SAME, bf16 in/out. 16 px/thread (4 rows x 4 cols).
// ---------------------------------------------------------------------------
__global__ __launch_bounds__(256)
void dwconv3(const u16* __restrict__ in, const float* __restrict__ wdw,
             u16* __restrict__ out)
{
    const int p  = blockIdx.y;                 // plane = bi*768 + ch
    const int t  = threadIdx.x;
    const int r0 = blockIdx.x * 32 + (t >> 5) * 4;
    const int c0 = (t & 31) << 2;

    const u16* plane = in + (size_t)p * HW;
    const float* wp = wdw + (p % NCH) * 9;
    float w[9];
    #pragma unroll
    for (int i = 0; i < 9; ++i) w[i] = wp[i];

    float rv[6][6];
    #pragma unroll
    for (int j = 0; j < 6; ++j) {
        const int ry = r0 - 1 + j;
        if (ry < 0 || ry >= IMGW) {
            #pragma unroll
            for (int k = 0; k < 6; ++k) rv[j][k] = 0.f;
        } else {
            const u16* rp = plane + ry * IMGW;
            ushort4 vm = *(const ushort4*)(rp + c0);
            rv[j][0] = (c0 > 0)   ? bf2f(rp[c0 - 1]) : 0.f;
            rv[j][1] = bf2f(vm.x); rv[j][2] = bf2f(vm.y);
            rv[j][3] = bf2f(vm.z); rv[j][4] = bf2f(vm.w);
            rv[j][5] = (c0 < 124) ? bf2f(rp[c0 + 4]) : 0.f;
        }
    }

    #pragma unroll
    for (int rr = 0; rr < 4; ++rr) {
        float acc[4] = {0.f, 0.f, 0.f, 0.f};
        #pragma unroll
        for (int dy = 0; dy < 3; ++dy) {
            #pragma unroll
            for (int dx = 0; dx < 3; ++dx) {
                float wv = w[dy * 3 + dx];
                #pragma unroll
                for (int q = 0; q < 4; ++q)
                    acc[q] = fmaf(rv[rr + dy][q + dx], wv, acc[q]);
            }
        }
        ushort4 o4;
        o4.x = f2bf(acc[0]); o4.y = f2bf(acc[1]);
        o4.z = f2bf(acc[2]); o4.w = f2bf(acc[3]);
        *(ushort4*)(out + (size_t)p * HW + (r0 + rr) * IMGW + c0) = o4;
    }
}

// ---------------------------------------------------------------------------
// K4: Gram via MFMA, fragments loaded DIRECTLY from global (no LDS staging).
// grid (32 n-chunks, 16 bh), 4 waves/block. Wave handles 128 n = 4 k-steps.
// Frag pattern: row = lane&15 (+16), k-span = (lane>>4)*8 -> lanes
// {r,r+16,r+32,r+48} read one contiguous 64B run per row (coalesced).
// Sumsq (l2norm) folded in from the loaded fragments.
// part: [chunk][bh][32*32]; sumsqp: [chunk][bh][64]
// ---------------------------------------------------------------------------
__global__ __launch_bounds__(256)
void gram_mfma(const u16* __restrict__ dw, float* __restrict__ part,
               float* __restrict__ sumsqp)
{
    __shared__ float pl[4][32][32];
    __shared__ float sl[4][64];
    const int chunk = blockIdx.x;    // 0..31
    const int bh    = blockIdx.y;
    const int bi = bh >> 3, h = bh & 7;
    const u16* qbase = dw + ((size_t)bi * NCH + h * CPH) * HW;
    const u16* kbase = dw + ((size_t)bi * NCH + 256 + h * CPH) * HW;
    const int t = threadIdx.x, lane = t & 63, w = t >> 6;
    const int lr = lane & 15;        // operand row / C col
    const int lg = lane >> 4;        // k-subspan / C row-group

    f32x4 acc[2][2];
    #pragma unroll
    for (int i = 0; i < 2; ++i)
        #pragma unroll
        for (int j = 0; j < 2; ++j)
            acc[i][j] = (f32x4){0.f, 0.f, 0.f, 0.f};
    float sq[4] = {0.f, 0.f, 0.f, 0.f};   // q[lr], q[lr+16], k[lr], k[lr+16]

    #pragma unroll
    for (int ks = 0; ks < 4; ++ks) {
        const int nb = chunk * 512 + w * 128 + ks * 32 + lg * 8;
        bf16x8 a0 = *(const bf16x8*)(qbase + (size_t)lr * HW + nb);
        bf16x8 a1 = *(const bf16x8*)(qbase + (size_t)(lr + 16) * HW + nb);
        bf16x8 b0 = *(const bf16x8*)(kbase + (size_t)lr * HW + nb);
        bf16x8 b1 = *(const bf16x8*)(kbase + (size_t)(lr + 16) * HW + nb);
        acc[0][0] = __builtin_amdgcn_mfma_f32_16x16x32_bf16(a0, b0, acc[0][0], 0, 0, 0);
        acc[0][1] = __builtin_amdgcn_mfma_f32_16x16x32_bf16(a0, b1, acc[0][1], 0, 0, 0);
        acc[1][0] = __builtin_amdgcn_mfma_f32_16x16x32_bf16(a1, b0, acc[1][0], 0, 0, 0);
        acc[1][1] = __builtin_amdgcn_mfma_f32_16x16x32_bf16(a1, b1, acc[1][1], 0, 0, 0);
        #pragma unroll
        for (int e = 0; e < 8; ++e) {
            float f0 = bf2f((u16)a0[e]); sq[0] = fmaf(f0, f0, sq[0]);
            float f1 = bf2f((u16)a1[e]); sq[1] = fmaf(f1, f1, sq[1]);
            float f2 = bf2f((u16)b0[e]); sq[2] = fmaf(f2, f2, sq[2]);
            float f3 = bf2f((u16)b1[e]); sq[3] = fmaf(f3, f3, sq[3]);
        }
    }
    // reduce sumsq across the 4 k-subspan lane groups (same lr)
    #pragma unroll
    for (int i = 0; i < 4; ++i) {
        sq[i] += __shfl_xor(sq[i], 16);
        sq[i] += __shfl_xor(sq[i], 32);
    }
    if (lane < 16) {
        sl[w][lane]      = sq[0];
        sl[w][16 + lane] = sq[1];
        sl[w][32 + lane] = sq[2];
        sl[w][48 + lane] = sq[3];
    }
    // write per-wave C partial: C[m=qt*16+lg*4+r][n=kt*16+lr]
    #pragma unroll
    for (int qt = 0; qt < 2; ++qt)
        #pragma unroll
        for (int kt = 0; kt < 2; ++kt)
            #pragma unroll
            for (int r = 0; r < 4; ++r)
                pl[w][qt * 16 + lg * 4 + r][kt * 16 + lr] = acc[qt][kt][r];
    __syncthreads();

    // block reduce 4 waves -> part / sumsqp
    #pragma unroll
    for (int i = 0; i < 4; ++i) {
        const int o = i * 256 + t;
        const int qc = o >> 5, kd = o & 31;
        float s = pl[0][qc][kd] + pl[1][qc][kd] + pl[2][qc][kd] + pl[3][qc][kd];
        part[((size_t)chunk * 16 + bh) * 1024 + o] = s;
    }
    if (t < 64) {
        float s = sl[0][t] + sl[1][t] + sl[2][t] + sl[3][t];
        sumsqp[((size_t)chunk * 16 + bh) * 64 + t] = s;
    }
}

// ---------------------------------------------------------------------------
// K4b: reduce partials + apply inv norms (from sumsq partials) and temperature
// ---------------------------------------------------------------------------
__global__ __launch_bounds__(256)
void gram_finish(const float* __restrict__ part, const float* __restrict__ sumsqp,
                 const float* __restrict__ temp, float* __restrict__ attn)
{
    const int idx = blockIdx.x * 256 + threadIdx.x;  // 0..16383
    const int bh = idx >> 10;
    const int h = bh & 7;
    const int c = (idx >> 5) & 31, d = idx & 31;
    float s = 0.f, sqq = 0.f, sqk = 0.f;
    #pragma unroll
    for (int ch = 0; ch < 32; ++ch) {
        s   += part[(size_t)ch * 16384 + idx];
        sqq += sumsqp[((size_t)ch * 16 + bh) * 64 + c];
        sqk += sumsqp[((size_t)ch * 16 + bh) * 64 + 32 + d];
    }
    float iq = 1.f / fmaxf(sqrtf(sqq), 1e-12f);
    float ik = 1.f / fmaxf(sqrtf(sqk), 1e-12f);
    attn[idx] = s * iq * ik * temp[h];
}

// ---------------------------------------------------------------------------
// K5: rank-based 4-way sparse softmax combine. One block (1024 thr) per bh.
// ---------------------------------------------------------------------------
__global__ __launch_bounds__(1024)
void sparse_softmax(const float* __restrict__ attn, float* __restrict__ spar,
                    const float* __restrict__ a1, const float* __restrict__ a2,
                    const float* __restrict__ a3, const float* __restrict__ a4)
{
    __shared__ float xs[1024];
    __shared__ float red[16 * 4];
    __shared__ float vthr[4];
    __shared__ float msh;
    __shared__ float ssh[4];

    const int bh = blockIdx.x, t = threadIdx.x;
    float x = attn[bh * 1024 + t];
    xs[t] = x;
    __syncthreads();

    int g = 0, e = 0;
    for (int j = 0; j < 1024; ++j) {
        float v = xs[j];
        g += (v > x);
        e += (v == x);
    }
    if (g == 0) msh = x;  // all writers hold the identical max value
    const int topks[4] = {512, 682, 768, 819};
    #pragma unroll
    for (int kk = 0; kk < 4; ++kk)
        if (g <= topks[kk] - 1 && topks[kk] - 1 < g + e) vthr[kk] = x;  // rank-(topk-1) value
    __syncthreads();

    float m  = msh;
    float ex = expf(x - m);
    float v4[4];
    #pragma unroll
    for (int kk = 0; kk < 4; ++kk) v4[kk] = (x >= vthr[kk]) ? ex : 0.f;
    #pragma unroll
    for (int off = 32; off; off >>= 1)
        #pragma unroll
        for (int kk = 0; kk < 4; ++kk) v4[kk] += __shfl_down(v4[kk], off);
    const int lane = t & 63, wid = t >> 6;
    if (lane == 0) {
        #pragma unroll
        for (int kk = 0; kk < 4; ++kk) red[wid * 4 + kk] = v4[kk];
    }
    __syncthreads();
    if (t == 0) {
        float s0 = 0, s1 = 0, s2 = 0, s3 = 0;
        for (int w = 0; w < 16; ++w) {
            s0 += red[w * 4 + 0]; s1 += red[w * 4 + 1];
            s2 += red[w * 4 + 2]; s3 += red[w * 4 + 3];
        }
        ssh[0] = s0; ssh[1] = s1; ssh[2] = s2; ssh[3] = s3;
    }
    __syncthreads();

    float av[4] = {*a1, *a2, *a3, *a4};
    float coef = 0.f;
    #pragma unroll
    for (int kk = 0; kk < 4; ++kk)
        if (x >= vthr[kk]) coef += av[kk] / ssh[kk];
    spar[bh * 1024 + t] = ex * coef;
}

// ---------------------------------------------------------------------------
// K6: M2[b][o][hd] = sum_cc Wproj[o][h*32+cc]*spar[b,h,cc,d]; emit split bf16
// in MFMA A-layout: row = b*2048 + s*256 + o (s=hd>>5), 32 c-slots quad-swizzled
// ---------------------------------------------------------------------------
__global__ __launch_bounds__(256)
void build_m2_split(const float* __restrict__ wproj, const float* __restrict__ spar,
                    u16* __restrict__ m2h, u16* __restrict__ m2l)
{
    const int idx = blockIdx.x * 256 + threadIdx.x;  // 0..131071
    const int b = idx >> 16, o = (idx >> 8) & 255, hd = idx & 255;
    const int h = hd >> 5, d = hd & 31;
    const float* wrow = wproj + o * 256 + h * CPH;
    const float* sp = spar + (size_t)(b * 8 + h) * 1024 + d;
    float acc = 0.f;
    #pragma unroll 8
    for (int cc = 0; cc < 32; ++cc)
        acc = fmaf(wrow[cc], sp[cc * 32], acc);
    u16 hi = f2bf(acc);
    u16 lo = f2bf(acc - bf2f(hi));
    const int s = hd >> 5, cslot = hd & 31;
    const int qt = cslot >> 3, e = cslot & 7;
    const int p = (o >> 1) & 3;
    size_t pos = ((size_t)(b * 2048 + s * 256 + o) << 5) + ((qt ^ p) << 3) + e;
    m2h[pos] = hi;
    m2l[pos] = lo;
}

// ---------------------------------------------------------------------------
// launch
// ---------------------------------------------------------------------------
extern "C" void kernel_launch(void* const* d_in, const int* in_sizes, int n_in,
                              void* d_out, int out_size, void* d_ws, size_t ws_size,
                              hipStream_t stream)
{
    const float* x      = (const float*)d_in[0];
    const float* w_qkv  = (const float*)d_in[1];
    const float* w_dw   = (const float*)d_in[2];
    const float* w_proj = (const float*)d_in[3];
    const float* temp   = (const float*)d_in[4];
    const float* a1     = (const float*)d_in[5];
    const float* a2     = (const float*)d_in[6];
    const float* a3     = (const float*)d_in[7];
    const float* a4     = (const float*)d_in[8];

    float* ws = (float*)d_ws;
    // region 0 floats [0, 25165824):
    //   qkvb bf16 [2][768][HW] (12582912 f-worth), dead after dwconv;
    //   vth  bf16 at f-ofs 12582912 (4194304 f-worth), written post-dwconv;
    //   small buffers overlay [0, ~640k) post-dwconv.
    // region 1 floats [25165824, ...): xth/xtl/wh/wl during K1', then dwb bf16.
    u16* qkvb = (u16*)ws;
    u16* vth  = (u16*)(ws + 12582912);
    float* sumsqp = ws;                      // 32*16*64 = 32768 floats
    float* part = ws + 32768;                // 32*16*1024 = 524288 floats
    float* attn = ws + 32768 + 524288;       // 16384 floats
    float* spar = attn + 16384;              // 16384 floats
    u16* m2h = (u16*)(spar + 16384);         // 131072 u16
    u16* m2l = m2h + 131072;                 // 131072 u16
    float* r1 = ws + (size_t)25165824;
    u16* xth = (u16*)r1;                     // 8388608 u16
    u16* xtl = xth + (size_t)8388608;
    u16* whp = xtl + (size_t)8388608;        // 196608 u16
    u16* wlp = whp + (size_t)196608;
    u16* dwb = (u16*)r1;                     // [2][768][HW] bf16 (after K1')

    // T1/T2: split W, transpose+split x (pre-swizzled for LDS banks)
    wsplit<<<24, 256, 0, stream>>>(w_qkv, whp, wlp);
    transp_split<<<dim3(1024, 2), 256, 0, stream>>>(x, (long)DIMC * HW, xth, xtl);
    // K1': qkv = W_qkv @ x (split-bf16 MFMA, 2-phase, XCD swizzle, bf16 out)
    gemm_mfma_split<true, true, 6><<<1536, 256, 0, stream>>>(
        whp, wlp, xth, xtl, qkvb, 0, 768, (long)NCH * HW);
    // K2: depthwise 3x3 (bf16 in/out)
    dwconv3<<<dim3(4, NB * NCH), 256, 0, stream>>>(qkvb, w_dw, dwb);
    // T3: transpose v (bf16, hi only)
    transp_bf<<<dim3(1024, 2), 256, 0, stream>>>(
        dwb + (size_t)512 * HW, (long)NCH * HW, vth);
    // K4: Gram via direct-from-global MFMA + fused sumsq, then finish
    gram_mfma<<<dim3(32, 16), 256, 0, stream>>>(dwb, part, sumsqp);
    gram_finish<<<64, 256, 0, stream>>>(part, sumsqp, temp, attn);
    // K5: 4-way sparse softmax combine
    sparse_softmax<<<16, 1024, 0, stream>>>(attn, spar, a1, a2, a3, a4);
    // K6: fold proj @ spar into split-bf16 M2 (MFMA A-layout)
    build_m2_split<<<512, 256, 0, stream>>>(w_proj, spar, m2h, m2l);
    // K7': out = M2 @ v (2-product split MFMA, fp32 out)
    gemm_mfma_split<false, false, 2><<<512, 256, 0, stream>>>(
        m2h, m2l, vth, nullptr, d_out, 2048, 256, (long)DIMC * HW);
}